// Round 3
// baseline (661.949 us; speedup 1.0000x reference)
//
// resubmit r3: identical pipeline (prior two rounds died on broker infra,
// kernel never executed)
#include <hip/hip_runtime.h>

typedef unsigned short u16;
typedef __attribute__((ext_vector_type(8))) short bf16x8;
typedef __attribute__((ext_vector_type(4))) short bf16x4;
typedef __attribute__((ext_vector_type(4))) float f32x4;

#define DEVINL static __device__ __forceinline__

// bf16 <-> f32 without depending on hip_bf16.h type semantics (RNE rounding)
DEVINL u16 f2bf(float x) {
  unsigned u = __float_as_uint(x);
  unsigned r = (u + 0x7FFFu + ((u >> 16) & 1u)) >> 16;
  return (u16)r;
}
DEVINL float bf2f(u16 h) { return __uint_as_float(((unsigned)h) << 16); }

// async global->LDS, 16B per lane (wave-uniform LDS base + lane*16 pattern)
DEVINL void gload_lds16(const u16* g, u16* l) {
  __builtin_amdgcn_global_load_lds(
      (const __attribute__((address_space(1))) void*)g,
      (__attribute__((address_space(3))) void*)l, 16, 0, 0);
}

// ---------------------------------------------------------------------------
// GEMM: C[M,N] = op( A[M,K] * B[N,K]^T )  (both contraction-contiguous)
// A_F32: A is fp32, converted to bf16 during reg-staging
// HAS_BIAS: += bias[col] (fp32)
// RESID: += resid[row*N+col] (fp32)
// OUT_F32: C stored fp32, else bf16
// 128x128 tile, BK=32, 4 waves (2x2), each wave 64x64 via 4x4 16x16x32 MFMAs
// ---------------------------------------------------------------------------
template <bool A_F32, bool HAS_BIAS, bool RESID, bool OUT_F32>
__global__ __launch_bounds__(256) void gemm_bt(
    const void* __restrict__ Ap, const u16* __restrict__ Bp,
    const float* __restrict__ bias, const float* __restrict__ resid,
    void* __restrict__ Cp, int M, int N, int K,
    long long Az, long long Bz, long long Cz, float scale) {
  (void)M;
  const int z = blockIdx.z;
  const int m0 = blockIdx.y * 128, n0 = blockIdx.x * 128;
  const int tid = threadIdx.x, lane = tid & 63, wv = tid >> 6;
  const int wr = wv >> 1, wc = wv & 1, lr = lane & 15, lh = lane >> 4;

  __shared__ u16 lA[128 * 32];
  __shared__ u16 lB[128 * 32];

  const u16* B = Bp + (size_t)z * Bz;
  const float* A32 = nullptr;
  const u16* A16 = nullptr;
  if constexpr (A_F32)
    A32 = (const float*)Ap + (size_t)z * Az;
  else
    A16 = (const u16*)Ap + (size_t)z * Az;

  f32x4 acc[4][4] = {};

  for (int k0 = 0; k0 < K; k0 += 32) {
    // ---- stage A tile [128][32] ----
    if constexpr (A_F32) {
#pragma unroll
      for (int i = 0; i < 2; i++) {
        int e = (i * 256 + tid) * 8;
        int r = e >> 5, c = e & 31;
        const float* src = A32 + (size_t)(m0 + r) * K + k0 + c;
        f32x4 v0 = *(const f32x4*)src;
        f32x4 v1 = *(const f32x4*)(src + 4);
        bf16x8 h;
        h[0] = (short)f2bf(v0[0]); h[1] = (short)f2bf(v0[1]);
        h[2] = (short)f2bf(v0[2]); h[3] = (short)f2bf(v0[3]);
        h[4] = (short)f2bf(v1[0]); h[5] = (short)f2bf(v1[1]);
        h[6] = (short)f2bf(v1[2]); h[7] = (short)f2bf(v1[3]);
        *(bf16x8*)&lA[e] = h;
      }
    } else {
#pragma unroll
      for (int i = 0; i < 2; i++) {
        int e = (i * 256 + tid) * 8;
        int r = e >> 5, c = e & 31;
        gload_lds16(A16 + (size_t)(m0 + r) * K + k0 + c, &lA[e]);
      }
    }
    // ---- stage B tile [128][32] ----
#pragma unroll
    for (int i = 0; i < 2; i++) {
      int e = (i * 256 + tid) * 8;
      int r = e >> 5, c = e & 31;
      gload_lds16(B + (size_t)(n0 + r) * K + k0 + c, &lB[e]);
    }
    __syncthreads();

    bf16x8 af[4], bfv[4];
#pragma unroll
    for (int m = 0; m < 4; m++)
      af[m] = *(const bf16x8*)&lA[(wr * 64 + m * 16 + lr) * 32 + lh * 8];
#pragma unroll
    for (int n = 0; n < 4; n++)
      bfv[n] = *(const bf16x8*)&lB[(wc * 64 + n * 16 + lr) * 32 + lh * 8];
#pragma unroll
    for (int m = 0; m < 4; m++)
#pragma unroll
      for (int n = 0; n < 4; n++)
        acc[m][n] = __builtin_amdgcn_mfma_f32_16x16x32_bf16(af[m], bfv[n],
                                                            acc[m][n], 0, 0, 0);
    __syncthreads();
  }

  // ---- epilogue: C/D layout col=lane&15, row=(lane>>4)*4+reg ----
  float* Cf = nullptr;
  u16* Ch = nullptr;
  if constexpr (OUT_F32)
    Cf = (float*)Cp + (size_t)z * Cz;
  else
    Ch = (u16*)Cp + (size_t)z * Cz;
#pragma unroll
  for (int m = 0; m < 4; m++) {
#pragma unroll
    for (int j = 0; j < 4; j++) {
      int row = m0 + wr * 64 + m * 16 + lh * 4 + j;
#pragma unroll
      for (int n = 0; n < 4; n++) {
        int col = n0 + wc * 64 + n * 16 + lr;
        float val = acc[m][n][j] * scale;
        if constexpr (HAS_BIAS) val += bias[col];
        if constexpr (RESID) val += resid[(size_t)row * N + col];
        if constexpr (OUT_F32)
          Cf[(size_t)row * N + col] = val;
        else
          Ch[(size_t)row * N + col] = f2bf(val);
      }
    }
  }
}

// ---------------------------------------------------------------------------
// fp32 -> bf16 convert (weights)
// ---------------------------------------------------------------------------
__global__ __launch_bounds__(256) void cvt_f32_bf16(const float* __restrict__ in,
                                                    u16* __restrict__ out,
                                                    int n) {
  int i = (blockIdx.x * 256 + threadIdx.x) * 4;
  if (i >= n) return;
  f32x4 v = *(const f32x4*)&in[i];
  bf16x4 o;
#pragma unroll
  for (int u = 0; u < 4; u++) o[u] = (short)f2bf(v[u]);
  *(bf16x4*)&out[i] = o;
}

// ---------------------------------------------------------------------------
// bf16 transpose per batch: in [R,C] -> out [C,R], 64x64 LDS tiles
// ---------------------------------------------------------------------------
__global__ __launch_bounds__(256) void transpose_bf16(const u16* __restrict__ in,
                                                      u16* __restrict__ out,
                                                      int R, int C) {
  const int z = blockIdx.z;
  const u16* I = in + (size_t)z * R * C;
  u16* O = out + (size_t)z * R * C;
  __shared__ u16 t[64][72];
  const int r0 = blockIdx.y * 64, c0 = blockIdx.x * 64;
  const int tid = threadIdx.x;
#pragma unroll
  for (int i = 0; i < 2; i++) {
    int e = (i * 256 + tid) * 8;
    int r = e >> 6, c = e & 63;
    bf16x8 v = *(const bf16x8*)&I[(size_t)(r0 + r) * C + c0 + c];
#pragma unroll
    for (int u = 0; u < 8; u++) t[r][c + u] = (u16)v[u];
  }
  __syncthreads();
#pragma unroll
  for (int i = 0; i < 2; i++) {
    int e = (i * 256 + tid) * 8;
    int orow = e >> 6, oc = e & 63;
    bf16x8 v;
#pragma unroll
    for (int u = 0; u < 8; u++) v[u] = (short)t[oc + u][orow];
    *(bf16x8*)&O[(size_t)(c0 + orow) * R + r0 + oc] = v;
  }
}

// ---------------------------------------------------------------------------
// row softmax in-place on bf16 rows of length C (C = 2048, 256 thr -> 8/thr)
// ---------------------------------------------------------------------------
__global__ __launch_bounds__(256) void softmax_rows(u16* __restrict__ p, int C) {
  const size_t base = (size_t)blockIdx.x * C;
  const int tid = threadIdx.x, lane = tid & 63, wv = tid >> 6;
  bf16x8 v = *(const bf16x8*)&p[base + tid * 8];
  float f[8];
#pragma unroll
  for (int u = 0; u < 8; u++) f[u] = bf2f((u16)v[u]);
  float mx = f[0];
#pragma unroll
  for (int u = 1; u < 8; u++) mx = fmaxf(mx, f[u]);
#pragma unroll
  for (int o = 32; o; o >>= 1) mx = fmaxf(mx, __shfl_xor(mx, o, 64));
  __shared__ float rm[4], rs[4];
  if (lane == 0) rm[wv] = mx;
  __syncthreads();
  mx = fmaxf(fmaxf(rm[0], rm[1]), fmaxf(rm[2], rm[3]));
  float s = 0.f, e[8];
#pragma unroll
  for (int u = 0; u < 8; u++) {
    e[u] = __expf(f[u] - mx);
    s += e[u];
  }
#pragma unroll
  for (int o = 32; o; o >>= 1) s += __shfl_xor(s, o, 64);
  if (lane == 0) rs[wv] = s;
  __syncthreads();
  s = rs[0] + rs[1] + rs[2] + rs[3];
  float inv = 1.f / s;
  bf16x8 o8;
#pragma unroll
  for (int u = 0; u < 8; u++) o8[u] = (short)f2bf(e[u] * inv);
  *(bf16x8*)&p[base + tid * 8] = o8;
}

// ---------------------------------------------------------------------------
// LayerNorm rows of 1024 fp32 -> d_out
// ---------------------------------------------------------------------------
__global__ __launch_bounds__(256) void ln_rows(const float* __restrict__ x,
                                               const float* __restrict__ gamma,
                                               const float* __restrict__ beta,
                                               float* __restrict__ out) {
  const size_t base = (size_t)blockIdx.x * 1024;
  const int tid = threadIdx.x, lane = tid & 63, wv = tid >> 6;
  f32x4 v = *(const f32x4*)&x[base + tid * 4];
  float s = v[0] + v[1] + v[2] + v[3];
  float q = v[0] * v[0] + v[1] * v[1] + v[2] * v[2] + v[3] * v[3];
#pragma unroll
  for (int o = 32; o; o >>= 1) {
    s += __shfl_xor(s, o, 64);
    q += __shfl_xor(q, o, 64);
  }
  __shared__ float rs[4], rq[4];
  if (lane == 0) {
    rs[wv] = s;
    rq[wv] = q;
  }
  __syncthreads();
  s = rs[0] + rs[1] + rs[2] + rs[3];
  q = rq[0] + rq[1] + rq[2] + rq[3];
  float mean = s * (1.f / 1024.f);
  float var = q * (1.f / 1024.f) - mean * mean;
  float rstd = rsqrtf(var + 1e-5f);
  f32x4 g = *(const f32x4*)&gamma[tid * 4];
  f32x4 b = *(const f32x4*)&beta[tid * 4];
  f32x4 o;
#pragma unroll
  for (int u = 0; u < 4; u++) o[u] = (v[u] - mean) * rstd * g[u] + b[u];
  *(f32x4*)&out[base + tid * 4] = o;
}

// ---------------------------------------------------------------------------
extern "C" void kernel_launch(void* const* d_in, const int* in_sizes, int n_in,
                              void* d_out, int out_size, void* d_ws,
                              size_t ws_size, hipStream_t stream) {
  (void)in_sizes; (void)n_in; (void)out_size; (void)ws_size;
  const float* q = (const float*)d_in[0];
  const float* k = (const float*)d_in[1];
  const float* v = (const float*)d_in[2];
  const float* Wq = (const float*)d_in[3];
  const float* Wk = (const float*)d_in[4];
  const float* bk = (const float*)d_in[5];
  const float* Wv = (const float*)d_in[6];
  const float* bv = (const float*)d_in[7];
  const float* Wo = (const float*)d_in[8];
  const float* bo = (const float*)d_in[9];
  const float* gamma = (const float*)d_in[10];
  const float* beta = (const float*)d_in[11];
  float* out = (float*)d_out;

  char* ws = (char*)d_ws;
  const size_t SZ_QKV = (size_t)16384 * 1024 * 2;  // 32 MiB
  u16* qh = (u16*)(ws);
  u16* kh = (u16*)(ws + SZ_QKV);
  u16* vh = (u16*)(ws + 2 * SZ_QKV);
  u16* vhT = (u16*)(ws + 3 * SZ_QKV);
  u16* probs = (u16*)(ws + 4 * SZ_QKV);        // 64 MiB (8 x 2048 x 2048 bf16)
  float* xbuf = (float*)(ws + 4 * SZ_QKV);     // overlays probs (dead by then)
  u16* attn = qh;                              // overlays qh (dead by then)
  u16* Wqb = (u16*)(ws + 4 * SZ_QKV + (size_t)67108864);
  u16* Wkb = Wqb + 1048576;
  u16* Wvb = Wkb + 1048576;
  u16* Wob = Wvb + 1048576;

  // weights -> bf16
  cvt_f32_bf16<<<1024, 256, 0, stream>>>(Wq, Wqb, 1048576);
  cvt_f32_bf16<<<1024, 256, 0, stream>>>(Wk, Wkb, 1048576);
  cvt_f32_bf16<<<1024, 256, 0, stream>>>(Wv, Wvb, 1048576);
  cvt_f32_bf16<<<1024, 256, 0, stream>>>(Wo, Wob, 1048576);

  // projections: [16384,1024] x [1024,1024]^T
  dim3 gp(8, 128, 1);
  gemm_bt<true, false, false, false><<<gp, 256, 0, stream>>>(
      q, Wqb, nullptr, nullptr, qh, 16384, 1024, 1024, 0, 0, 0, 0.125f);
  gemm_bt<true, true, false, false><<<gp, 256, 0, stream>>>(
      k, Wkb, bk, nullptr, kh, 16384, 1024, 1024, 0, 0, 0, 1.0f);
  gemm_bt<true, true, false, false><<<gp, 256, 0, stream>>>(
      v, Wvb, bv, nullptr, vh, 16384, 1024, 1024, 0, 0, 0, 1.0f);

  // vh [b,2048,1024] -> vhT [b,1024,2048]
  transpose_bf16<<<dim3(16, 32, 8), 256, 0, stream>>>(vh, vhT, 2048, 1024);

  // scores = qh @ kh^T per batch -> probs buffer (bf16)
  gemm_bt<false, false, false, false><<<dim3(16, 16, 8), 256, 0, stream>>>(
      qh, kh, nullptr, nullptr, probs, 2048, 2048, 1024, 2097152LL, 2097152LL,
      4194304LL, 1.0f);

  // softmax rows in place
  softmax_rows<<<16384, 256, 0, stream>>>(probs, 2048);

  // attn = probs @ vhT^T per batch
  gemm_bt<false, false, false, false><<<dim3(8, 16, 8), 256, 0, stream>>>(
      probs, vhT, nullptr, nullptr, attn, 2048, 1024, 2048, 4194304LL,
      2097152LL, 2097152LL, 1.0f);

  // x = attn @ Wo^T + bo + q  (fp32)
  gemm_bt<false, true, true, true><<<dim3(8, 128, 1), 256, 0, stream>>>(
      attn, Wob, bo, q, xbuf, 16384, 1024, 1024, 0, 0, 0, 1.0f);

  // LayerNorm -> out
  ln_rows<<<16384, 256, 0, stream>>>(xbuf, gamma, beta, out);
}

// Round 4
// 552.359 us; speedup vs baseline: 1.1984x; 1.1984x over previous
//
#include <hip/hip_runtime.h>

typedef unsigned short u16;
typedef __attribute__((ext_vector_type(8))) short bf16x8;
typedef __attribute__((ext_vector_type(4))) float f32x4;

#define DEVINL static __device__ __forceinline__

// bf16 <-> f32 (RNE rounding)
DEVINL u16 f2bf(float x) {
  unsigned u = __float_as_uint(x);
  unsigned r = (u + 0x7FFFu + ((u >> 16) & 1u)) >> 16;
  return (u16)r;
}
DEVINL float bf2f(u16 h) { return __uint_as_float(((unsigned)h) << 16); }

// async global->LDS, 16B per lane (wave-uniform LDS base + lane*16 pattern)
DEVINL void gload_lds16(const u16* g, u16* l) {
  __builtin_amdgcn_global_load_lds(
      (const __attribute__((address_space(1))) void*)g,
      (__attribute__((address_space(3))) void*)l, 16, 0, 0);
}

// Stage one [128][32] bf16 tile pair into LDS.
// LDS dest is LINEAR (gload_lds requirement); the XOR swizzle is applied to
// the per-lane GLOBAL source instead (rule-21 both-sides pattern):
//   LDS 16B-granule g holds global slot (g&3)^((g>>4)&3) of row g>>2,
// so the ds_read side XORs slot with row bits 2-3 -> 2 lanes/bank (free).
DEVINL void stage_pair(const u16* Abase, const u16* Bbase, int K, u16* la,
                       u16* lb, int tid) {
#pragma unroll
  for (int i = 0; i < 2; i++) {
    int g = i * 256 + tid;
    int row = g >> 2;
    int slot = (g & 3) ^ ((g >> 4) & 3);
    gload_lds16(Abase + (size_t)row * K + slot * 8, &la[g * 8]);
  }
#pragma unroll
  for (int i = 0; i < 2; i++) {
    int g = i * 256 + tid;
    int row = g >> 2;
    int slot = (g & 3) ^ ((g >> 4) & 3);
    gload_lds16(Bbase + (size_t)row * K + slot * 8, &lb[g * 8]);
  }
}

// ---------------------------------------------------------------------------
// GEMM: C[M,N] = scale*(A[M,K] (bf16) * B[N,K]^T (bf16)) [+bias] [+resid]
// 128x128 tile, BK=32, 4 waves (2x2), 16x16x32 bf16 MFMA.
// 3-buffer LDS, 2-deep prefetch, counted vmcnt(4), raw barriers.
// Bijective XCD block swizzle (all launches have nwg % 8 == 0).
// ---------------------------------------------------------------------------
template <bool HAS_BIAS, bool RESID, bool OUT_F32>
__global__ __launch_bounds__(256) void gemm_bt(
    const u16* __restrict__ Ap, const u16* __restrict__ Bp,
    const float* __restrict__ bias, const float* __restrict__ resid,
    void* __restrict__ Cp, int N, int K, long long Az, long long Bz,
    long long Cz, float scale) {
  const int gx = gridDim.x, gy = gridDim.y;
  int lin = blockIdx.x + gx * (blockIdx.y + gy * blockIdx.z);
  const int nwg = gx * gy * gridDim.z;
  if ((nwg & 7) == 0) {
    const int chunk = nwg >> 3;
    lin = (lin & 7) * chunk + (lin >> 3);
  }
  const int bz = lin / (gx * gy);
  const int rem = lin - bz * gx * gy;
  const int m0 = (rem / gx) * 128, n0 = (rem % gx) * 128;

  const int tid = threadIdx.x, lane = tid & 63, wv = tid >> 6;
  const int wr = wv >> 1, wc = wv & 1, lr = lane & 15, lh = lane >> 4;

  __shared__ u16 sA[3][4096];
  __shared__ u16 sB[3][4096];

  const u16* A = Ap + (size_t)bz * Az + (size_t)m0 * K;
  const u16* B = Bp + (size_t)bz * Bz + (size_t)n0 * K;

  f32x4 acc[4][4] = {};
  const int nt = K >> 5;  // >= 32 for all our shapes

  // prologue: stage tiles 0 and 1 (8 loads in flight), wait for tile 0
  stage_pair(A, B, K, sA[0], sB[0], tid);
  stage_pair(A + 32, B + 32, K, sA[1], sB[1], tid);
  asm volatile("s_waitcnt vmcnt(4)" ::: "memory");
  __builtin_amdgcn_s_barrier();
  asm volatile("" ::: "memory");

  int cur = 0;
  for (int t = 0; t < nt; ++t) {
    if (t + 2 < nt) {
      int nx = cur + 2;
      if (nx >= 3) nx -= 3;
      stage_pair(A + (t + 2) * 32, B + (t + 2) * 32, K, sA[nx], sB[nx], tid);
    }
    const u16* la = sA[cur];
    const u16* lb = sB[cur];
    bf16x8 af[4], bfv[4];
#pragma unroll
    for (int m = 0; m < 4; m++) {
      int row = wr * 64 + m * 16 + lr;
      int slot = lh ^ ((row >> 2) & 3);
      af[m] = *(const bf16x8*)&la[row * 32 + slot * 8];
    }
#pragma unroll
    for (int n = 0; n < 4; n++) {
      int row = wc * 64 + n * 16 + lr;
      int slot = lh ^ ((row >> 2) & 3);
      bfv[n] = *(const bf16x8*)&lb[row * 32 + slot * 8];
    }
#pragma unroll
    for (int m = 0; m < 4; m++)
#pragma unroll
      for (int n = 0; n < 4; n++)
        acc[m][n] = __builtin_amdgcn_mfma_f32_16x16x32_bf16(af[m], bfv[n],
                                                            acc[m][n], 0, 0, 0);
    // tile t+1 must be resident before next iter: drain all but tile t+2's
    // 4 loads (counted vmcnt, never 0 in steady state). lgkmcnt(0) closes the
    // ds_read-vs-next-stage-DMA overwrite window.
    if (t + 2 < nt)
      asm volatile("s_waitcnt vmcnt(4) lgkmcnt(0)" ::: "memory");
    else
      asm volatile("s_waitcnt vmcnt(0) lgkmcnt(0)" ::: "memory");
    __builtin_amdgcn_s_barrier();
    asm volatile("" ::: "memory");
    if (++cur == 3) cur = 0;
  }

  // epilogue: C/D layout col=lane&15, row=(lane>>4)*4+reg
  float* Cf = nullptr;
  u16* Ch = nullptr;
  if constexpr (OUT_F32)
    Cf = (float*)Cp + (size_t)bz * Cz;
  else
    Ch = (u16*)Cp + (size_t)bz * Cz;
#pragma unroll
  for (int m = 0; m < 4; m++) {
#pragma unroll
    for (int j = 0; j < 4; j++) {
      int row = m0 + wr * 64 + m * 16 + lh * 4 + j;
#pragma unroll
      for (int n = 0; n < 4; n++) {
        int col = n0 + wc * 64 + n * 16 + lr;
        float val = acc[m][n][j] * scale;
        if constexpr (HAS_BIAS) val += bias[col];
        if constexpr (RESID) val += resid[(size_t)row * N + col];
        if constexpr (OUT_F32)
          Cf[(size_t)row * N + col] = val;
        else
          Ch[(size_t)row * N + col] = f2bf(val);
      }
    }
  }
}

// ---------------------------------------------------------------------------
// fp32 -> bf16 convert, 8 elems/thread (grid sized exactly)
// ---------------------------------------------------------------------------
__global__ __launch_bounds__(256) void cvt8(const float* __restrict__ in,
                                            u16* __restrict__ out) {
  const size_t i = ((size_t)blockIdx.x * 256 + threadIdx.x) * 8;
  f32x4 a = *(const f32x4*)&in[i];
  f32x4 b = *(const f32x4*)&in[i + 4];
  bf16x8 h;
#pragma unroll
  for (int u = 0; u < 4; u++) h[u] = (short)f2bf(a[u]);
#pragma unroll
  for (int u = 0; u < 4; u++) h[4 + u] = (short)f2bf(b[u]);
  *(bf16x8*)&out[i] = h;
}

// ---------------------------------------------------------------------------
// bf16 transpose per batch: in [R,C] -> out [C,R], 64x64 LDS tiles
// ---------------------------------------------------------------------------
__global__ __launch_bounds__(256) void transpose_bf16(const u16* __restrict__ in,
                                                      u16* __restrict__ out,
                                                      int R, int C) {
  const int z = blockIdx.z;
  const u16* I = in + (size_t)z * R * C;
  u16* O = out + (size_t)z * R * C;
  __shared__ u16 t[64][72];
  const int r0 = blockIdx.y * 64, c0 = blockIdx.x * 64;
  const int tid = threadIdx.x;
#pragma unroll
  for (int i = 0; i < 2; i++) {
    int e = (i * 256 + tid) * 8;
    int r = e >> 6, c = e & 63;
    bf16x8 v = *(const bf16x8*)&I[(size_t)(r0 + r) * C + c0 + c];
#pragma unroll
    for (int u = 0; u < 8; u++) t[r][c + u] = (u16)v[u];
  }
  __syncthreads();
#pragma unroll
  for (int i = 0; i < 2; i++) {
    int e = (i * 256 + tid) * 8;
    int orow = e >> 6, oc = e & 63;
    bf16x8 v;
#pragma unroll
    for (int u = 0; u < 8; u++) v[u] = (short)t[oc + u][orow];
    *(bf16x8*)&O[(size_t)(c0 + orow) * R + r0 + oc] = v;
  }
}

// ---------------------------------------------------------------------------
// row softmax in-place on bf16 rows of length 2048 (256 thr -> 8/thr)
// ---------------------------------------------------------------------------
__global__ __launch_bounds__(256) void softmax_rows(u16* __restrict__ p) {
  const size_t base = (size_t)blockIdx.x * 2048;
  const int tid = threadIdx.x, lane = tid & 63, wv = tid >> 6;
  bf16x8 v = *(const bf16x8*)&p[base + tid * 8];
  float f[8];
#pragma unroll
  for (int u = 0; u < 8; u++) f[u] = bf2f((u16)v[u]);
  float mx = f[0];
#pragma unroll
  for (int u = 1; u < 8; u++) mx = fmaxf(mx, f[u]);
#pragma unroll
  for (int o = 32; o; o >>= 1) mx = fmaxf(mx, __shfl_xor(mx, o, 64));
  __shared__ float rm[4], rs[4];
  if (lane == 0) rm[wv] = mx;
  __syncthreads();
  mx = fmaxf(fmaxf(rm[0], rm[1]), fmaxf(rm[2], rm[3]));
  float s = 0.f, e[8];
#pragma unroll
  for (int u = 0; u < 8; u++) {
    e[u] = __expf(f[u] - mx);
    s += e[u];
  }
#pragma unroll
  for (int o = 32; o; o >>= 1) s += __shfl_xor(s, o, 64);
  if (lane == 0) rs[wv] = s;
  __syncthreads();
  s = rs[0] + rs[1] + rs[2] + rs[3];
  float inv = 1.f / s;
  bf16x8 o8;
#pragma unroll
  for (int u = 0; u < 8; u++) o8[u] = (short)f2bf(e[u] * inv);
  *(bf16x8*)&p[base + tid * 8] = o8;
}

// ---------------------------------------------------------------------------
// LayerNorm rows of 1024 fp32 -> d_out
// ---------------------------------------------------------------------------
__global__ __launch_bounds__(256) void ln_rows(const float* __restrict__ x,
                                               const float* __restrict__ gamma,
                                               const float* __restrict__ beta,
                                               float* __restrict__ out) {
  const size_t base = (size_t)blockIdx.x * 1024;
  const int tid = threadIdx.x, lane = tid & 63, wv = tid >> 6;
  f32x4 v = *(const f32x4*)&x[base + tid * 4];
  float s = v[0] + v[1] + v[2] + v[3];
  float q = v[0] * v[0] + v[1] * v[1] + v[2] * v[2] + v[3] * v[3];
#pragma unroll
  for (int o = 32; o; o >>= 1) {
    s += __shfl_xor(s, o, 64);
    q += __shfl_xor(q, o, 64);
  }
  __shared__ float rs[4], rq[4];
  if (lane == 0) {
    rs[wv] = s;
    rq[wv] = q;
  }
  __syncthreads();
  s = rs[0] + rs[1] + rs[2] + rs[3];
  q = rq[0] + rq[1] + rq[2] + rq[3];
  float mean = s * (1.f / 1024.f);
  float var = q * (1.f / 1024.f) - mean * mean;
  float rstd = rsqrtf(var + 1e-5f);
  f32x4 g = *(const f32x4*)&gamma[tid * 4];
  f32x4 b = *(const f32x4*)&beta[tid * 4];
  f32x4 o;
#pragma unroll
  for (int u = 0; u < 4; u++) o[u] = (v[u] - mean) * rstd * g[u] + b[u];
  *(f32x4*)&out[base + tid * 4] = o;
}

// ---------------------------------------------------------------------------
extern "C" void kernel_launch(void* const* d_in, const int* in_sizes, int n_in,
                              void* d_out, int out_size, void* d_ws,
                              size_t ws_size, hipStream_t stream) {
  (void)in_sizes; (void)n_in; (void)out_size; (void)ws_size;
  const float* q = (const float*)d_in[0];
  const float* k = (const float*)d_in[1];
  const float* v = (const float*)d_in[2];
  const float* Wq = (const float*)d_in[3];
  const float* Wk = (const float*)d_in[4];
  const float* bk = (const float*)d_in[5];
  const float* Wv = (const float*)d_in[6];
  const float* bv = (const float*)d_in[7];
  const float* Wo = (const float*)d_in[8];
  const float* bo = (const float*)d_in[9];
  const float* gamma = (const float*)d_in[10];
  const float* beta = (const float*)d_in[11];
  float* out = (float*)d_out;

  char* ws = (char*)d_ws;
  const size_t SZ_QKV = (size_t)16384 * 1024 * 2;  // 32 MiB
  u16* qh = (u16*)(ws);
  u16* kh = (u16*)(ws + SZ_QKV);
  u16* vh = (u16*)(ws + 2 * SZ_QKV);
  u16* vhT = (u16*)(ws + 3 * SZ_QKV);
  u16* probs = (u16*)(ws + 4 * SZ_QKV);     // 64 MiB, alive scores->PV
  u16* qkvb = probs;                        // 32 MiB A-cvt slot, dead by scores
  float* xbuf = (float*)(ws + 4 * SZ_QKV);  // overlays probs (dead by outproj)
  u16* attn = qh;                           // overlays qh (dead after scores)
  u16* Wqb = (u16*)(ws + 4 * SZ_QKV + (size_t)67108864);
  u16* Wkb = Wqb + 1048576;
  u16* Wvb = Wkb + 1048576;
  u16* Wob = Wvb + 1048576;

  // weights -> bf16
  cvt8<<<512, 256, 0, stream>>>(Wq, Wqb);
  cvt8<<<512, 256, 0, stream>>>(Wk, Wkb);
  cvt8<<<512, 256, 0, stream>>>(Wv, Wvb);
  cvt8<<<512, 256, 0, stream>>>(Wo, Wob);

  // projections: cvt input -> bf16 slot, then [16384,1024] x [1024,1024]^T
  dim3 gp(8, 128, 1);
  cvt8<<<8192, 256, 0, stream>>>(q, qkvb);
  gemm_bt<false, false, false><<<gp, 256, 0, stream>>>(
      qkvb, Wqb, nullptr, nullptr, qh, 1024, 1024, 0, 0, 0, 0.125f);
  cvt8<<<8192, 256, 0, stream>>>(k, qkvb);
  gemm_bt<true, false, false><<<gp, 256, 0, stream>>>(
      qkvb, Wkb, bk, nullptr, kh, 1024, 1024, 0, 0, 0, 1.0f);
  cvt8<<<8192, 256, 0, stream>>>(v, qkvb);
  gemm_bt<true, false, false><<<gp, 256, 0, stream>>>(
      qkvb, Wvb, bv, nullptr, vh, 1024, 1024, 0, 0, 0, 1.0f);

  // vh [b,2048,1024] -> vhT [b,1024,2048]
  transpose_bf16<<<dim3(16, 32, 8), 256, 0, stream>>>(vh, vhT, 2048, 1024);

  // scores = qh @ kh^T per batch -> probs (bf16)
  gemm_bt<false, false, false><<<dim3(16, 16, 8), 256, 0, stream>>>(
      qh, kh, nullptr, nullptr, probs, 2048, 1024, 2097152LL, 2097152LL,
      4194304LL, 1.0f);

  // softmax rows in place
  softmax_rows<<<16384, 256, 0, stream>>>(probs);

  // attn = probs @ vhT^T per batch
  gemm_bt<false, false, false><<<dim3(8, 16, 8), 256, 0, stream>>>(
      probs, vhT, nullptr, nullptr, attn, 1024, 2048, 4194304LL, 2097152LL,
      2097152LL, 1.0f);

  // x = attn @ Wo^T + bo + q  (fp32)
  gemm_bt<true, true, true><<<dim3(8, 128, 1), 256, 0, stream>>>(
      attn, Wob, bo, q, xbuf, 1024, 1024, 0, 0, 0, 1.0f);

  // LayerNorm -> out
  ln_rows<<<16384, 256, 0, stream>>>(xbuf, gamma, beta, out);
}

// Round 5
// 437.040 us; speedup vs baseline: 1.5146x; 1.2639x over previous
//
#include <hip/hip_runtime.h>

typedef unsigned short u16;
typedef __attribute__((ext_vector_type(8))) short bf16x8;
typedef __attribute__((ext_vector_type(4))) float f32x4;

#define DEVINL static __device__ __forceinline__

// bf16 <-> f32 (RNE rounding)
DEVINL u16 f2bf(float x) {
  unsigned u = __float_as_uint(x);
  unsigned r = (u + 0x7FFFu + ((u >> 16) & 1u)) >> 16;
  return (u16)r;
}
DEVINL float bf2f(u16 h) { return __uint_as_float(((unsigned)h) << 16); }

// async global->LDS, 16B per lane (wave-uniform LDS base + lane*16 pattern)
DEVINL void gload_lds16(const u16* g, u16* l) {
  __builtin_amdgcn_global_load_lds(
      (const __attribute__((address_space(1))) void*)g,
      (__attribute__((address_space(3))) void*)l, 16, 0, 0);
}

// Stage one operand tile [256][32] bf16 into LDS (2 gload instr per wave).
// LDS dest LINEAR (gload requirement); XOR swizzle applied to the per-lane
// GLOBAL source (rule-21 both-sides): LDS 16B-granule q holds global granule
// (q&3)^((q>>4)&3) of row q>>2. ds_read side XORs granule with row bits 2-3.
// Balanced: 2 lanes/bank per wave64 b128 read (free per m136).
DEVINL void stage_half(const u16* gbase, int K, u16* ldst, int tid) {
#pragma unroll
  for (int i = 0; i < 2; i++) {
    int q = i * 512 + tid;
    int r = q >> 2, gl = (q & 3) ^ ((q >> 4) & 3);
    gload_lds16(gbase + (size_t)r * K + gl * 8, ldst + q * 8);
  }
}

// ---------------------------------------------------------------------------
// GEMM: C[M,N] = scale*(A[M,K] bf16 * B[N,K]^T bf16) [+bias] [+resid]
// 256x256 tile, BK=32, 512 thr (8 waves 2Mx4N, wave owns 128x64).
// 3-buffer LDS (96KB), 2 phases/tile, counted vmcnt(4) (never 0 steady-state),
// one barrier per K-tile, setprio around MFMA clusters, XCD block swizzle.
// Load ledger: tile t+2 staged during compute(t) into buffer of t-1 (reads
// done before the t-1 -> t barrier => no WAR race); boundary vmcnt(4) leaves
// t+2's 4 loads in flight (~2-tile HBM latency cover).
// ---------------------------------------------------------------------------
template <bool HAS_BIAS, bool RESID, bool OUT_F32>
__global__ __launch_bounds__(512, 2) void gemm_bt(
    const u16* __restrict__ Ap, const u16* __restrict__ Bp,
    const float* __restrict__ bias, const float* __restrict__ resid,
    void* __restrict__ Cp, int N, int K, long long Az, long long Bz,
    long long Cz, float scale) {
  const int gx = gridDim.x, gy = gridDim.y;
  int lin = blockIdx.x + gx * (blockIdx.y + gy * blockIdx.z);
  const int nwg = gx * gy * gridDim.z;
  if ((nwg & 7) == 0) {
    const int chunk = nwg >> 3;
    lin = (lin & 7) * chunk + (lin >> 3);
  }
  const int bz = lin / (gx * gy);
  const int rem = lin - bz * gx * gy;
  const int m0 = (rem / gx) * 256, n0 = (rem % gx) * 256;

  const int tid = threadIdx.x, lane = tid & 63, wv = tid >> 6;
  const int wr = wv >> 2, wc = wv & 3, lr = lane & 15, lh = lane >> 4;

  // 3 bufs x (A 8192 + B 8192) u16 = 96 KB
  __shared__ u16 lds[3 * 16384];

  const u16* A = Ap + (size_t)bz * Az + (size_t)m0 * K;
  const u16* B = Bp + (size_t)bz * Bz + (size_t)n0 * K;

  f32x4 acc[8][4] = {};
  const int nt = K >> 5;  // >= 32 for all our shapes

  // prologue: stage tiles 0,1 (8 instr/wave); wait tile 0 (leave t1 in flight)
  stage_half(A, K, &lds[0], tid);
  stage_half(B, K, &lds[8192], tid);
  stage_half(A + 32, K, &lds[16384], tid);
  stage_half(B + 32, K, &lds[16384 + 8192], tid);
  asm volatile("s_waitcnt vmcnt(4)" ::: "memory");
  __builtin_amdgcn_s_barrier();

  int d = 0;
  for (int t = 0; t < nt; ++t) {
    const u16* la = &lds[d * 16384];
    const u16* lb = la + 8192;
    int dn = d + 2;
    if (dn >= 3) dn -= 3;
    const bool doPre = (t + 2) < nt;

    // ---- phase 0: B frags + A frags m0..3, stage A of tile t+2 ----
    bf16x8 bfv[4], af[4];
#pragma unroll
    for (int n = 0; n < 4; n++) {
      int row = wc * 64 + n * 16 + lr;
      bfv[n] = *(const bf16x8*)&lb[row * 32 + (lh ^ ((row >> 2) & 3)) * 8];
    }
#pragma unroll
    for (int m = 0; m < 4; m++) {
      int row = wr * 128 + m * 16 + lr;
      af[m] = *(const bf16x8*)&la[row * 32 + (lh ^ ((row >> 2) & 3)) * 8];
    }
    if (doPre) stage_half(A + (size_t)(t + 2) * 32, K, &lds[dn * 16384], tid);
    __builtin_amdgcn_s_setprio(1);
#pragma unroll
    for (int m = 0; m < 4; m++)
#pragma unroll
      for (int n = 0; n < 4; n++)
        acc[m][n] = __builtin_amdgcn_mfma_f32_16x16x32_bf16(af[m], bfv[n],
                                                            acc[m][n], 0, 0, 0);
    __builtin_amdgcn_s_setprio(0);

    // ---- phase 1: A frags m4..7, stage B of tile t+2 ----
#pragma unroll
    for (int m = 0; m < 4; m++) {
      int row = wr * 128 + (m + 4) * 16 + lr;
      af[m] = *(const bf16x8*)&la[row * 32 + (lh ^ ((row >> 2) & 3)) * 8];
    }
    if (doPre)
      stage_half(B + (size_t)(t + 2) * 32, K, &lds[dn * 16384 + 8192], tid);
    __builtin_amdgcn_s_setprio(1);
#pragma unroll
    for (int m = 0; m < 4; m++)
#pragma unroll
      for (int n = 0; n < 4; n++)
        acc[m + 4][n] = __builtin_amdgcn_mfma_f32_16x16x32_bf16(
            af[m], bfv[n], acc[m + 4][n], 0, 0, 0);
    __builtin_amdgcn_s_setprio(0);

    // ---- tile boundary: counted vmcnt, one barrier ----
    if (t + 2 < nt)
      asm volatile("s_waitcnt vmcnt(4)" ::: "memory");
    else if (t + 1 < nt)
      asm volatile("s_waitcnt vmcnt(0)" ::: "memory");
    if (t + 1 < nt) __builtin_amdgcn_s_barrier();
    if (++d == 3) d = 0;
  }

  // epilogue: C/D layout col=lane&15, row=(lane>>4)*4+reg
  float* Cf = nullptr;
  u16* Ch = nullptr;
  if constexpr (OUT_F32)
    Cf = (float*)Cp + (size_t)bz * Cz;
  else
    Ch = (u16*)Cp + (size_t)bz * Cz;
#pragma unroll
  for (int m = 0; m < 8; m++) {
#pragma unroll
    for (int j = 0; j < 4; j++) {
      int row = m0 + wr * 128 + m * 16 + lh * 4 + j;
#pragma unroll
      for (int n = 0; n < 4; n++) {
        int col = n0 + wc * 64 + n * 16 + lr;
        float val = acc[m][n][j] * scale;
        if constexpr (HAS_BIAS) val += bias[col];
        if constexpr (RESID) val += resid[(size_t)row * N + col];
        if constexpr (OUT_F32)
          Cf[(size_t)row * N + col] = val;
        else
          Ch[(size_t)row * N + col] = f2bf(val);
      }
    }
  }
}

// ---------------------------------------------------------------------------
// fp32 -> bf16 convert, 8 elems/thread (grid sized exactly)
// ---------------------------------------------------------------------------
__global__ __launch_bounds__(256) void cvt8(const float* __restrict__ in,
                                            u16* __restrict__ out) {
  const size_t i = ((size_t)blockIdx.x * 256 + threadIdx.x) * 8;
  f32x4 a = *(const f32x4*)&in[i];
  f32x4 b = *(const f32x4*)&in[i + 4];
  bf16x8 h;
#pragma unroll
  for (int u = 0; u < 4; u++) h[u] = (short)f2bf(a[u]);
#pragma unroll
  for (int u = 0; u < 4; u++) h[4 + u] = (short)f2bf(b[u]);
  *(bf16x8*)&out[i] = h;
}

// ---------------------------------------------------------------------------
// bf16 transpose per batch: in [R,C] -> out [C,R], 64x64 LDS tiles
// ---------------------------------------------------------------------------
__global__ __launch_bounds__(256) void transpose_bf16(const u16* __restrict__ in,
                                                      u16* __restrict__ out,
                                                      int R, int C) {
  const int z = blockIdx.z;
  const u16* I = in + (size_t)z * R * C;
  u16* O = out + (size_t)z * R * C;
  __shared__ u16 t[64][72];
  const int r0 = blockIdx.y * 64, c0 = blockIdx.x * 64;
  const int tid = threadIdx.x;
#pragma unroll
  for (int i = 0; i < 2; i++) {
    int e = (i * 256 + tid) * 8;
    int r = e >> 6, c = e & 63;
    bf16x8 v = *(const bf16x8*)&I[(size_t)(r0 + r) * C + c0 + c];
#pragma unroll
    for (int u = 0; u < 8; u++) t[r][c + u] = (u16)v[u];
  }
  __syncthreads();
#pragma unroll
  for (int i = 0; i < 2; i++) {
    int e = (i * 256 + tid) * 8;
    int orow = e >> 6, oc = e & 63;
    bf16x8 v;
#pragma unroll
    for (int u = 0; u < 8; u++) v[u] = (short)t[oc + u][orow];
    *(bf16x8*)&O[(size_t)(c0 + orow) * R + r0 + oc] = v;
  }
}

// ---------------------------------------------------------------------------
// row softmax in-place on bf16 rows of length 2048 (256 thr -> 8/thr)
// ---------------------------------------------------------------------------
__global__ __launch_bounds__(256) void softmax_rows(u16* __restrict__ p) {
  const size_t base = (size_t)blockIdx.x * 2048;
  const int tid = threadIdx.x, lane = tid & 63, wv = tid >> 6;
  bf16x8 v = *(const bf16x8*)&p[base + tid * 8];
  float f[8];
#pragma unroll
  for (int u = 0; u < 8; u++) f[u] = bf2f((u16)v[u]);
  float mx = f[0];
#pragma unroll
  for (int u = 1; u < 8; u++) mx = fmaxf(mx, f[u]);
#pragma unroll
  for (int o = 32; o; o >>= 1) mx = fmaxf(mx, __shfl_xor(mx, o, 64));
  __shared__ float rm[4], rs[4];
  if (lane == 0) rm[wv] = mx;
  __syncthreads();
  mx = fmaxf(fmaxf(rm[0], rm[1]), fmaxf(rm[2], rm[3]));
  float s = 0.f, e[8];
#pragma unroll
  for (int u = 0; u < 8; u++) {
    e[u] = __expf(f[u] - mx);
    s += e[u];
  }
#pragma unroll
  for (int o = 32; o; o >>= 1) s += __shfl_xor(s, o, 64);
  if (lane == 0) rs[wv] = s;
  __syncthreads();
  s = rs[0] + rs[1] + rs[2] + rs[3];
  float inv = 1.f / s;
  bf16x8 o8;
#pragma unroll
  for (int u = 0; u < 8; u++) o8[u] = (short)f2bf(e[u] * inv);
  *(bf16x8*)&p[base + tid * 8] = o8;
}

// ---------------------------------------------------------------------------
// LayerNorm rows of 1024 fp32 -> d_out
// ---------------------------------------------------------------------------
__global__ __launch_bounds__(256) void ln_rows(const float* __restrict__ x,
                                               const float* __restrict__ gamma,
                                               const float* __restrict__ beta,
                                               float* __restrict__ out) {
  const size_t base = (size_t)blockIdx.x * 1024;
  const int tid = threadIdx.x, lane = tid & 63, wv = tid >> 6;
  f32x4 v = *(const f32x4*)&x[base + tid * 4];
  float s = v[0] + v[1] + v[2] + v[3];
  float q = v[0] * v[0] + v[1] * v[1] + v[2] * v[2] + v[3] * v[3];
#pragma unroll
  for (int o = 32; o; o >>= 1) {
    s += __shfl_xor(s, o, 64);
    q += __shfl_xor(q, o, 64);
  }
  __shared__ float rs[4], rq[4];
  if (lane == 0) {
    rs[wv] = s;
    rq[wv] = q;
  }
  __syncthreads();
  s = rs[0] + rs[1] + rs[2] + rs[3];
  q = rq[0] + rq[1] + rq[2] + rq[3];
  float mean = s * (1.f / 1024.f);
  float var = q * (1.f / 1024.f) - mean * mean;
  float rstd = rsqrtf(var + 1e-5f);
  f32x4 g = *(const f32x4*)&gamma[tid * 4];
  f32x4 b = *(const f32x4*)&beta[tid * 4];
  f32x4 o;
#pragma unroll
  for (int u = 0; u < 4; u++) o[u] = (v[u] - mean) * rstd * g[u] + b[u];
  *(f32x4*)&out[base + tid * 4] = o;
}

// ---------------------------------------------------------------------------
extern "C" void kernel_launch(void* const* d_in, const int* in_sizes, int n_in,
                              void* d_out, int out_size, void* d_ws,
                              size_t ws_size, hipStream_t stream) {
  (void)in_sizes; (void)n_in; (void)out_size; (void)ws_size;
  const float* q = (const float*)d_in[0];
  const float* k = (const float*)d_in[1];
  const float* v = (const float*)d_in[2];
  const float* Wq = (const float*)d_in[3];
  const float* Wk = (const float*)d_in[4];
  const float* bk = (const float*)d_in[5];
  const float* Wv = (const float*)d_in[6];
  const float* bv = (const float*)d_in[7];
  const float* Wo = (const float*)d_in[8];
  const float* bo = (const float*)d_in[9];
  const float* gamma = (const float*)d_in[10];
  const float* beta = (const float*)d_in[11];
  float* out = (float*)d_out;

  char* ws = (char*)d_ws;
  const size_t SZ_QKV = (size_t)16384 * 1024 * 2;  // 32 MiB
  u16* qh = (u16*)(ws);
  u16* kh = (u16*)(ws + SZ_QKV);
  u16* vh = (u16*)(ws + 2 * SZ_QKV);
  u16* vhT = (u16*)(ws + 3 * SZ_QKV);
  u16* probs = (u16*)(ws + 4 * SZ_QKV);     // 64 MiB, alive scores->PV
  u16* qkvb = probs;                        // 32 MiB A-cvt slot, dead by scores
  float* xbuf = (float*)(ws + 4 * SZ_QKV);  // overlays probs (dead by outproj)
  u16* attn = qh;                           // overlays qh (dead after scores)
  u16* Wqb = (u16*)(ws + 4 * SZ_QKV + (size_t)67108864);
  u16* Wkb = Wqb + 1048576;
  u16* Wvb = Wkb + 1048576;
  u16* Wob = Wvb + 1048576;

  // weights -> bf16
  cvt8<<<512, 256, 0, stream>>>(Wq, Wqb);
  cvt8<<<512, 256, 0, stream>>>(Wk, Wkb);
  cvt8<<<512, 256, 0, stream>>>(Wv, Wvb);
  cvt8<<<512, 256, 0, stream>>>(Wo, Wob);

  // projections: cvt input -> bf16 slot, then [16384,1024] x [1024,1024]^T
  dim3 gp(4, 64, 1);  // 256 blocks of 256x256
  cvt8<<<8192, 256, 0, stream>>>(q, qkvb);
  gemm_bt<false, false, false><<<gp, 512, 0, stream>>>(
      qkvb, Wqb, nullptr, nullptr, qh, 1024, 1024, 0, 0, 0, 0.125f);
  cvt8<<<8192, 256, 0, stream>>>(k, qkvb);
  gemm_bt<true, false, false><<<gp, 512, 0, stream>>>(
      qkvb, Wkb, bk, nullptr, kh, 1024, 1024, 0, 0, 0, 1.0f);
  cvt8<<<8192, 256, 0, stream>>>(v, qkvb);
  gemm_bt<true, false, false><<<gp, 512, 0, stream>>>(
      qkvb, Wvb, bv, nullptr, vh, 1024, 1024, 0, 0, 0, 1.0f);

  // vh [b,2048,1024] -> vhT [b,1024,2048]
  transpose_bf16<<<dim3(16, 32, 8), 256, 0, stream>>>(vh, vhT, 2048, 1024);

  // scores = qh @ kh^T per batch -> probs (bf16)
  gemm_bt<false, false, false><<<dim3(8, 8, 8), 512, 0, stream>>>(
      qh, kh, nullptr, nullptr, probs, 2048, 1024, 2097152LL, 2097152LL,
      4194304LL, 1.0f);

  // softmax rows in place
  softmax_rows<<<16384, 256, 0, stream>>>(probs);

  // attn = probs @ vhT^T per batch
  gemm_bt<false, false, false><<<dim3(4, 8, 8), 512, 0, stream>>>(
      probs, vhT, nullptr, nullptr, attn, 1024, 2048, 4194304LL, 2097152LL,
      2097152LL, 1.0f);

  // x = attn @ Wo^T + bo + q  (fp32)
  gemm_bt<true, true, true><<<dim3(4, 64, 1), 512, 0, stream>>>(
      attn, Wob, bo, q, xbuf, 1024, 1024, 0, 0, 0, 1.0f);

  // LayerNorm -> out
  ln_rows<<<16384, 256, 0, stream>>>(xbuf, gamma, beta, out);
}

// Round 6
// 433.505 us; speedup vs baseline: 1.5270x; 1.0082x over previous
//
#include <hip/hip_runtime.h>

typedef unsigned short u16;
typedef __attribute__((ext_vector_type(8))) short bf16x8;
typedef __attribute__((ext_vector_type(4))) float f32x4;

#define DEVINL static __device__ __forceinline__

// bf16 <-> f32 (RNE rounding)
DEVINL u16 f2bf(float x) {
  unsigned u = __float_as_uint(x);
  unsigned r = (u + 0x7FFFu + ((u >> 16) & 1u)) >> 16;
  return (u16)r;
}
DEVINL float bf2f(u16 h) { return __uint_as_float(((unsigned)h) << 16); }

// async global->LDS, 16B per lane (wave-uniform LDS base + lane*16 pattern)
DEVINL void gload_lds16(const u16* g, u16* l) {
  __builtin_amdgcn_global_load_lds(
      (const __attribute__((address_space(1))) void*)g,
      (__attribute__((address_space(3))) void*)l, 16, 0, 0);
}

// Row-pair granule swizzle for a [256 rows][32 cols] bf16 operand tile.
// LDS granule g (16B) = row-pair p=g>>3, slot w=g&7; logical location:
//   w' = w ^ (p&7);  row = 2p + (w'>>2);  kslot = w'&3.
// Read of (row r, kslot s) -> granule swzg(r,s). Every 8-consecutive-lane
// subgroup of a wave64 b128 read hits all 8 bank-groups exactly once
// (enumerated) -> zero LDS bank conflicts. Staging keeps LDS dest linear
// (gload_lds requirement) and applies the inverse permutation to the
// per-lane GLOBAL source (rule-21 both-sides involution).
DEVINL int swzg(int r, int s) {
  return ((r >> 1) << 3) + ((((r & 1) << 2) | s) ^ ((r >> 1) & 7));
}

// Stage one operand tile [256][32] bf16 into LDS (2 gload instr per wave).
DEVINL void stage_half(const u16* gbase, int K, u16* ldst, int tid) {
#pragma unroll
  for (int i = 0; i < 2; i++) {
    int g = i * 512 + tid;
    int p = g >> 3;
    int w = (g & 7) ^ (p & 7);
    int row = p * 2 + (w >> 2);
    int ks = w & 3;
    gload_lds16(gbase + (size_t)row * K + ks * 8, ldst + g * 8);
  }
}

// ---------------------------------------------------------------------------
// GEMM: C[M,N] = scale*(A[M,K] bf16 * B[N,K]^T bf16) [+bias] [+resid]
// 256x256 tile, BK=32, 512 thr (8 waves 2Mx4N, wave owns 128x64).
// 3-buffer LDS (96KB), 2 phases/tile, counted vmcnt(4) (never 0 steady-state),
// one barrier per K-tile, setprio around MFMA clusters, XCD block swizzle.
// Load ledger: tile t+2 staged during compute(t) into buffer of t-1 (reads
// done before the t-1 -> t barrier => no WAR race); boundary vmcnt(4) leaves
// t+2's 4 loads in flight (~2-tile HBM latency cover).
// ---------------------------------------------------------------------------
template <bool HAS_BIAS, bool RESID, bool OUT_F32>
__global__ __launch_bounds__(512, 2) void gemm_bt(
    const u16* __restrict__ Ap, const u16* __restrict__ Bp,
    const float* __restrict__ bias, const float* __restrict__ resid,
    void* __restrict__ Cp, int N, int K, long long Az, long long Bz,
    long long Cz, float scale) {
  const int gx = gridDim.x, gy = gridDim.y;
  int lin = blockIdx.x + gx * (blockIdx.y + gy * blockIdx.z);
  const int nwg = gx * gy * gridDim.z;
  if ((nwg & 7) == 0) {
    const int chunk = nwg >> 3;
    lin = (lin & 7) * chunk + (lin >> 3);
  }
  const int bz = lin / (gx * gy);
  const int rem = lin - bz * gx * gy;
  const int m0 = (rem / gx) * 256, n0 = (rem % gx) * 256;

  const int tid = threadIdx.x, lane = tid & 63, wv = tid >> 6;
  const int wr = wv >> 2, wc = wv & 3, lr = lane & 15, lh = lane >> 4;

  // 3 bufs x (A 8192 + B 8192) u16 = 96 KB
  __shared__ u16 lds[3 * 16384];

  const u16* A = Ap + (size_t)bz * Az + (size_t)m0 * K;
  const u16* B = Bp + (size_t)bz * Bz + (size_t)n0 * K;

  f32x4 acc[8][4] = {};
  const int nt = K >> 5;

  // prologue: stage tiles 0,1 (8 instr/wave); wait tile 0 (leave t1 in flight)
  stage_half(A, K, &lds[0], tid);
  stage_half(B, K, &lds[8192], tid);
  stage_half(A + 32, K, &lds[16384], tid);
  stage_half(B + 32, K, &lds[16384 + 8192], tid);
  asm volatile("s_waitcnt vmcnt(4)" ::: "memory");
  __builtin_amdgcn_s_barrier();

  int d = 0;
  for (int t = 0; t < nt; ++t) {
    const u16* la = &lds[d * 16384];
    const u16* lb = la + 8192;
    int dn = d + 2;
    if (dn >= 3) dn -= 3;
    const bool doPre = (t + 2) < nt;

    // ---- phase 0: B frags + A frags m0..3, stage A of tile t+2 ----
    bf16x8 bfv[4], af[4];
#pragma unroll
    for (int n = 0; n < 4; n++) {
      int row = wc * 64 + n * 16 + lr;
      bfv[n] = *(const bf16x8*)&lb[swzg(row, lh) * 8];
    }
#pragma unroll
    for (int m = 0; m < 4; m++) {
      int row = wr * 128 + m * 16 + lr;
      af[m] = *(const bf16x8*)&la[swzg(row, lh) * 8];
    }
    if (doPre) stage_half(A + (size_t)(t + 2) * 32, K, &lds[dn * 16384], tid);
    __builtin_amdgcn_s_setprio(1);
#pragma unroll
    for (int m = 0; m < 4; m++)
#pragma unroll
      for (int n = 0; n < 4; n++)
        acc[m][n] = __builtin_amdgcn_mfma_f32_16x16x32_bf16(af[m], bfv[n],
                                                            acc[m][n], 0, 0, 0);
    __builtin_amdgcn_s_setprio(0);

    // ---- phase 1: A frags m4..7, stage B of tile t+2 ----
#pragma unroll
    for (int m = 0; m < 4; m++) {
      int row = wr * 128 + (m + 4) * 16 + lr;
      af[m] = *(const bf16x8*)&la[swzg(row, lh) * 8];
    }
    if (doPre)
      stage_half(B + (size_t)(t + 2) * 32, K, &lds[dn * 16384 + 8192], tid);
    __builtin_amdgcn_s_setprio(1);
#pragma unroll
    for (int m = 0; m < 4; m++)
#pragma unroll
      for (int n = 0; n < 4; n++)
        acc[m + 4][n] = __builtin_amdgcn_mfma_f32_16x16x32_bf16(
            af[m], bfv[n], acc[m + 4][n], 0, 0, 0);
    __builtin_amdgcn_s_setprio(0);

    // ---- tile boundary: counted vmcnt, one barrier ----
    if (t + 2 < nt)
      asm volatile("s_waitcnt vmcnt(4)" ::: "memory");
    else if (t + 1 < nt)
      asm volatile("s_waitcnt vmcnt(0)" ::: "memory");
    if (t + 1 < nt) __builtin_amdgcn_s_barrier();
    if (++d == 3) d = 0;
  }

  // epilogue: C/D layout col=lane&15, row=(lane>>4)*4+reg
  float* Cf = nullptr;
  u16* Ch = nullptr;
  if constexpr (OUT_F32)
    Cf = (float*)Cp + (size_t)bz * Cz;
  else
    Ch = (u16*)Cp + (size_t)bz * Cz;
#pragma unroll
  for (int m = 0; m < 8; m++) {
#pragma unroll
    for (int j = 0; j < 4; j++) {
      int row = m0 + wr * 128 + m * 16 + lh * 4 + j;
#pragma unroll
      for (int n = 0; n < 4; n++) {
        int col = n0 + wc * 64 + n * 16 + lr;
        float val = acc[m][n][j] * scale;
        if constexpr (HAS_BIAS) val += bias[col];
        if constexpr (RESID) val += resid[(size_t)row * N + col];
        if constexpr (OUT_F32)
          Cf[(size_t)row * N + col] = val;
        else
          Ch[(size_t)row * N + col] = f2bf(val);
      }
    }
  }
}

// ---------------------------------------------------------------------------
// fp32 -> bf16 convert, 8 elems/thread (grid sized exactly)
// ---------------------------------------------------------------------------
__global__ __launch_bounds__(256) void cvt8(const float* __restrict__ in,
                                            u16* __restrict__ out) {
  const size_t i = ((size_t)blockIdx.x * 256 + threadIdx.x) * 8;
  f32x4 a = *(const f32x4*)&in[i];
  f32x4 b = *(const f32x4*)&in[i + 4];
  bf16x8 h;
#pragma unroll
  for (int u = 0; u < 4; u++) h[u] = (short)f2bf(a[u]);
#pragma unroll
  for (int u = 0; u < 4; u++) h[4 + u] = (short)f2bf(b[u]);
  *(bf16x8*)&out[i] = h;
}

// ---------------------------------------------------------------------------
// bf16 transpose per batch: in [R,C] -> out [C,R], 64x64 LDS tiles
// ---------------------------------------------------------------------------
__global__ __launch_bounds__(256) void transpose_bf16(const u16* __restrict__ in,
                                                      u16* __restrict__ out,
                                                      int R, int C) {
  const int z = blockIdx.z;
  const u16* I = in + (size_t)z * R * C;
  u16* O = out + (size_t)z * R * C;
  __shared__ u16 t[64][72];
  const int r0 = blockIdx.y * 64, c0 = blockIdx.x * 64;
  const int tid = threadIdx.x;
#pragma unroll
  for (int i = 0; i < 2; i++) {
    int e = (i * 256 + tid) * 8;
    int r = e >> 6, c = e & 63;
    bf16x8 v = *(const bf16x8*)&I[(size_t)(r0 + r) * C + c0 + c];
#pragma unroll
    for (int u = 0; u < 8; u++) t[r][c + u] = (u16)v[u];
  }
  __syncthreads();
#pragma unroll
  for (int i = 0; i < 2; i++) {
    int e = (i * 256 + tid) * 8;
    int orow = e >> 6, oc = e & 63;
    bf16x8 v;
#pragma unroll
    for (int u = 0; u < 8; u++) v[u] = (short)t[oc + u][orow];
    *(bf16x8*)&O[(size_t)(c0 + orow) * R + r0 + oc] = v;
  }
}

// ---------------------------------------------------------------------------
// row softmax in-place on bf16 rows of length 2048 (256 thr -> 8/thr)
// ---------------------------------------------------------------------------
__global__ __launch_bounds__(256) void softmax_rows(u16* __restrict__ p) {
  const size_t base = (size_t)blockIdx.x * 2048;
  const int tid = threadIdx.x, lane = tid & 63, wv = tid >> 6;
  bf16x8 v = *(const bf16x8*)&p[base + tid * 8];
  float f[8];
#pragma unroll
  for (int u = 0; u < 8; u++) f[u] = bf2f((u16)v[u]);
  float mx = f[0];
#pragma unroll
  for (int u = 1; u < 8; u++) mx = fmaxf(mx, f[u]);
#pragma unroll
  for (int o = 32; o; o >>= 1) mx = fmaxf(mx, __shfl_xor(mx, o, 64));
  __shared__ float rm[4], rs[4];
  if (lane == 0) rm[wv] = mx;
  __syncthreads();
  mx = fmaxf(fmaxf(rm[0], rm[1]), fmaxf(rm[2], rm[3]));
  float s = 0.f, e[8];
#pragma unroll
  for (int u = 0; u < 8; u++) {
    e[u] = __expf(f[u] - mx);
    s += e[u];
  }
#pragma unroll
  for (int o = 32; o; o >>= 1) s += __shfl_xor(s, o, 64);
  if (lane == 0) rs[wv] = s;
  __syncthreads();
  s = rs[0] + rs[1] + rs[2] + rs[3];
  float inv = 1.f / s;
  bf16x8 o8;
#pragma unroll
  for (int u = 0; u < 8; u++) o8[u] = (short)f2bf(e[u] * inv);
  *(bf16x8*)&p[base + tid * 8] = o8;
}

// ---------------------------------------------------------------------------
// LayerNorm rows of 1024 fp32 -> d_out
// ---------------------------------------------------------------------------
__global__ __launch_bounds__(256) void ln_rows(const float* __restrict__ x,
                                               const float* __restrict__ gamma,
                                               const float* __restrict__ beta,
                                               float* __restrict__ out) {
  const size_t base = (size_t)blockIdx.x * 1024;
  const int tid = threadIdx.x, lane = tid & 63, wv = tid >> 6;
  f32x4 v = *(const f32x4*)&x[base + tid * 4];
  float s = v[0] + v[1] + v[2] + v[3];
  float q = v[0] * v[0] + v[1] * v[1] + v[2] * v[2] + v[3] * v[3];
#pragma unroll
  for (int o = 32; o; o >>= 1) {
    s += __shfl_xor(s, o, 64);
    q += __shfl_xor(q, o, 64);
  }
  __shared__ float rs[4], rq[4];
  if (lane == 0) {
    rs[wv] = s;
    rq[wv] = q;
  }
  __syncthreads();
  s = rs[0] + rs[1] + rs[2] + rs[3];
  q = rq[0] + rq[1] + rq[2] + rq[3];
  float mean = s * (1.f / 1024.f);
  float var = q * (1.f / 1024.f) - mean * mean;
  float rstd = rsqrtf(var + 1e-5f);
  f32x4 g = *(const f32x4*)&gamma[tid * 4];
  f32x4 b = *(const f32x4*)&beta[tid * 4];
  f32x4 o;
#pragma unroll
  for (int u = 0; u < 4; u++) o[u] = (v[u] - mean) * rstd * g[u] + b[u];
  *(f32x4*)&out[base + tid * 4] = o;
}

// ---------------------------------------------------------------------------
extern "C" void kernel_launch(void* const* d_in, const int* in_sizes, int n_in,
                              void* d_out, int out_size, void* d_ws,
                              size_t ws_size, hipStream_t stream) {
  (void)in_sizes; (void)n_in; (void)out_size; (void)ws_size;
  const float* q = (const float*)d_in[0];
  const float* k = (const float*)d_in[1];
  const float* v = (const float*)d_in[2];
  const float* Wq = (const float*)d_in[3];
  const float* Wk = (const float*)d_in[4];
  const float* bk = (const float*)d_in[5];
  const float* Wv = (const float*)d_in[6];
  const float* bv = (const float*)d_in[7];
  const float* Wo = (const float*)d_in[8];
  const float* bo = (const float*)d_in[9];
  const float* gamma = (const float*)d_in[10];
  const float* beta = (const float*)d_in[11];
  float* out = (float*)d_out;

  char* ws = (char*)d_ws;
  const size_t SZ_QKV = (size_t)16384 * 1024 * 2;  // 32 MiB
  u16* qh = (u16*)(ws);
  u16* kh = (u16*)(ws + SZ_QKV);
  u16* vh = (u16*)(ws + 2 * SZ_QKV);
  u16* vhT = (u16*)(ws + 3 * SZ_QKV);
  u16* probs = (u16*)(ws + 4 * SZ_QKV);     // 64 MiB, alive scores->PV
  u16* qkvb = probs;                        // 32 MiB A-cvt slot, dead by scores
  float* xbuf = (float*)(ws + 4 * SZ_QKV);  // overlays probs (dead by outproj)
  u16* attn = qh;                           // overlays qh (dead after scores)
  u16* Wqb = (u16*)(ws + 4 * SZ_QKV + (size_t)67108864);
  u16* Wkb = Wqb + 1048576;
  u16* Wvb = Wkb + 1048576;
  u16* Wob = Wvb + 1048576;

  // weights -> bf16
  cvt8<<<512, 256, 0, stream>>>(Wq, Wqb);
  cvt8<<<512, 256, 0, stream>>>(Wk, Wkb);
  cvt8<<<512, 256, 0, stream>>>(Wv, Wvb);
  cvt8<<<512, 256, 0, stream>>>(Wo, Wob);

  // projections: cvt input -> bf16 slot, then [16384,1024] x [1024,1024]^T
  dim3 gp(4, 64, 1);  // 256 blocks of 256x256
  cvt8<<<8192, 256, 0, stream>>>(q, qkvb);
  gemm_bt<false, false, false><<<gp, 512, 0, stream>>>(
      qkvb, Wqb, nullptr, nullptr, qh, 1024, 1024, 0, 0, 0, 0.125f);
  cvt8<<<8192, 256, 0, stream>>>(k, qkvb);
  gemm_bt<true, false, false><<<gp, 512, 0, stream>>>(
      qkvb, Wkb, bk, nullptr, kh, 1024, 1024, 0, 0, 0, 1.0f);
  cvt8<<<8192, 256, 0, stream>>>(v, qkvb);
  gemm_bt<true, false, false><<<gp, 512, 0, stream>>>(
      qkvb, Wvb, bv, nullptr, vh, 1024, 1024, 0, 0, 0, 1.0f);

  // vh [b,2048,1024] -> vhT [b,1024,2048]
  transpose_bf16<<<dim3(16, 32, 8), 256, 0, stream>>>(vh, vhT, 2048, 1024);

  // scores = qh @ kh^T per batch -> probs (bf16)
  gemm_bt<false, false, false><<<dim3(8, 8, 8), 512, 0, stream>>>(
      qh, kh, nullptr, nullptr, probs, 2048, 1024, 2097152LL, 2097152LL,
      4194304LL, 1.0f);

  // softmax rows in place
  softmax_rows<<<16384, 256, 0, stream>>>(probs);

  // attn = probs @ vhT^T per batch
  gemm_bt<false, false, false><<<dim3(4, 8, 8), 512, 0, stream>>>(
      probs, vhT, nullptr, nullptr, attn, 1024, 2048, 4194304LL, 2097152LL,
      2097152LL, 1.0f);

  // x = attn @ Wo^T + bo + q  (fp32)
  gemm_bt<true, true, true><<<dim3(4, 64, 1), 512, 0, stream>>>(
      attn, Wob, bo, q, xbuf, 1024, 1024, 0, 0, 0, 1.0f);

  // LayerNorm -> out
  ln_rows<<<16384, 256, 0, stream>>>(xbuf, gamma, beta, out);
}

// Round 7
// 428.907 us; speedup vs baseline: 1.5433x; 1.0107x over previous
//
#include <hip/hip_runtime.h>

typedef unsigned short u16;
typedef __attribute__((ext_vector_type(8))) short bf16x8;
typedef __attribute__((ext_vector_type(4))) float f32x4;

#define DEVINL static __device__ __forceinline__

// bf16 <-> f32 (RNE rounding)
DEVINL u16 f2bf(float x) {
  unsigned u = __float_as_uint(x);
  unsigned r = (u + 0x7FFFu + ((u >> 16) & 1u)) >> 16;
  return (u16)r;
}
DEVINL float bf2f(u16 h) { return __uint_as_float(((unsigned)h) << 16); }

// async global->LDS, 16B per lane (wave-uniform LDS base + lane*16 pattern)
DEVINL void gload_lds16(const u16* g, u16* l) {
  __builtin_amdgcn_global_load_lds(
      (const __attribute__((address_space(1))) void*)g,
      (__attribute__((address_space(3))) void*)l, 16, 0, 0);
}

// ---------------------------------------------------------------------------
// Swizzled [256 rows][64 cols] bf16 operand tile, 8 granules (16B) per row.
// Granule column for logical (row r, slot s in 0..7):  c = s ^ (r & 7).
// Bank group = granule column -> every 8-consecutive-lane subgroup of a
// wave64 ds_read_b128 covers all 8 bank groups exactly once => zero
// conflicts (verified by the r6 counter: 6.3M -> 0 with this family).
// Staging keeps LDS dest LINEAR (gload_lds requirement) and applies the
// inverse permutation to the per-lane GLOBAL source (rule-21 involution).
// ---------------------------------------------------------------------------
DEVINL void stage64(const u16* gbase, int K, u16* ldst, int tid) {
#pragma unroll
  for (int i = 0; i < 4; i++) {
    int g = i * 512 + tid;
    int r = g >> 3;
    int ks = (g & 7) ^ (r & 7);
    gload_lds16(gbase + (size_t)r * K + ks * 8, ldst + g * 8);
  }
}

// ---------------------------------------------------------------------------
// GEMM: C[M,N] = scale*(A[M,K] bf16 * B[N,K]^T bf16) [+bias] [+resid]
// 256x256 tile, BK=64, 512 thr (8 waves 2Mx4N, wave owns 128x64), m201-style
// 8-phase schedule: per K-tile 4 phases, each {ds_read frags ∥ stage ->
// barrier -> lgkmcnt(0) -> setprio(1) 16 MFMA setprio(0) -> barrier}.
// 2-buffer LDS (128KB). Tile T+1 staged during tile T phases 0-1 into the
// other buffer (its previous occupant T-1 was fully read before tile T
// began => no WAR race). Boundary vmcnt(0) at phase 3 waits on loads >= 2
// phases old (~free). B-frags read once per tile (phase 0) and held in regs.
// ---------------------------------------------------------------------------
template <bool HAS_BIAS, bool RESID, bool OUT_F32>
__global__ __launch_bounds__(512, 2) void gemm_bt(
    const u16* __restrict__ Ap, const u16* __restrict__ Bp,
    const float* __restrict__ bias, const float* __restrict__ resid,
    void* __restrict__ Cp, int N, int K, long long Az, long long Bz,
    long long Cz, float scale) {
  const int gx = gridDim.x, gy = gridDim.y;
  int lin = blockIdx.x + gx * (blockIdx.y + gy * blockIdx.z);
  const int nwg = gx * gy * gridDim.z;
  if ((nwg & 7) == 0) {
    const int chunk = nwg >> 3;
    lin = (lin & 7) * chunk + (lin >> 3);
  }
  const int bz = lin / (gx * gy);
  const int rem = lin - bz * gx * gy;
  const int m0 = (rem / gx) * 256, n0 = (rem % gx) * 256;

  const int tid = threadIdx.x, lane = tid & 63, wv = tid >> 6;
  const int wr = wv >> 2, wc = wv & 3, lr = lane & 15, lh = lane >> 4;

  // 2 bufs x (A [256][64] + B [256][64]) bf16 = 128 KB
  __shared__ u16 lds[65536];

  const u16* A = Ap + (size_t)bz * Az + (size_t)m0 * K;
  const u16* B = Bp + (size_t)bz * Bz + (size_t)n0 * K;

  f32x4 acc[8][4] = {};
  const int nt = K >> 6;  // K % 64 == 0 for all our shapes

  // prologue: stage tile 0 into buf0, drain, barrier
  stage64(A, K, &lds[0], tid);
  stage64(B, K, &lds[16384], tid);
  asm volatile("s_waitcnt vmcnt(0)" ::: "memory");
  __builtin_amdgcn_s_barrier();

  for (int T = 0; T < nt; ++T) {
    u16* bufA = &lds[(T & 1) * 32768];
    u16* bufB = bufA + 16384;
    u16* nbufA = &lds[((T + 1) & 1) * 32768];
    u16* nbufB = nbufA + 16384;
    const bool pre = (T + 1) < nt;
    bf16x8 bf[4][2];  // B-frags held across the tile's 4 phases

#pragma unroll
    for (int p = 0; p < 4; ++p) {
      // ---- ds_read frags for this phase ----
      bf16x8 af[2][2];
#pragma unroll
      for (int i = 0; i < 2; ++i) {
        int r = wr * 128 + (2 * p + i) * 16 + lr;
#pragma unroll
        for (int h = 0; h < 2; ++h)
          af[i][h] =
              *(const bf16x8*)&bufA[(r * 8 + (((h << 2) | lh) ^ (r & 7))) * 8];
      }
      if (p == 0) {
#pragma unroll
        for (int n = 0; n < 4; ++n) {
          int r = wc * 64 + n * 16 + lr;
#pragma unroll
          for (int h = 0; h < 2; ++h)
            bf[n][h] =
                *(const bf16x8*)&bufB[(r * 8 + (((h << 2) | lh) ^ (r & 7))) * 8];
        }
        if (pre) stage64(A + (size_t)(T + 1) * 64, K, nbufA, tid);
        asm volatile("s_waitcnt lgkmcnt(8)" ::: "memory");  // 12-read phase
      }
      if (p == 1 && pre) stage64(B + (size_t)(T + 1) * 64, K, nbufB, tid);

      __builtin_amdgcn_s_barrier();
      asm volatile("s_waitcnt lgkmcnt(0)" ::: "memory");
      __builtin_amdgcn_sched_barrier(0);  // rule 18: pin MFMA below the wait

      __builtin_amdgcn_s_setprio(1);
#pragma unroll
      for (int i = 0; i < 2; ++i)
#pragma unroll
        for (int n = 0; n < 4; ++n)
#pragma unroll
          for (int h = 0; h < 2; ++h)
            acc[2 * p + i][n] = __builtin_amdgcn_mfma_f32_16x16x32_bf16(
                af[i][h], bf[n][h], acc[2 * p + i][n], 0, 0, 0);
      __builtin_amdgcn_s_setprio(0);

      // tile boundary: wait next tile's DMA (issued phases 0-1, >=2 phases
      // old => ~free), then the phase's trailing barrier admits it.
      if (p == 3 && pre) asm volatile("s_waitcnt vmcnt(0)" ::: "memory");
      if (!(p == 3 && !pre)) __builtin_amdgcn_s_barrier();
    }
  }

  // epilogue: C/D layout col=lane&15, row=(lane>>4)*4+reg
  float* Cf = nullptr;
  u16* Ch = nullptr;
  if constexpr (OUT_F32)
    Cf = (float*)Cp + (size_t)bz * Cz;
  else
    Ch = (u16*)Cp + (size_t)bz * Cz;
#pragma unroll
  for (int m = 0; m < 8; m++) {
#pragma unroll
    for (int j = 0; j < 4; j++) {
      int row = m0 + wr * 128 + m * 16 + lh * 4 + j;
#pragma unroll
      for (int n = 0; n < 4; n++) {
        int col = n0 + wc * 64 + n * 16 + lr;
        float val = acc[m][n][j] * scale;
        if constexpr (HAS_BIAS) val += bias[col];
        if constexpr (RESID) val += resid[(size_t)row * N + col];
        if constexpr (OUT_F32)
          Cf[(size_t)row * N + col] = val;
        else
          Ch[(size_t)row * N + col] = f2bf(val);
      }
    }
  }
}

// ---------------------------------------------------------------------------
// fp32 -> bf16 convert, 8 elems/thread (grid sized exactly)
// ---------------------------------------------------------------------------
__global__ __launch_bounds__(256) void cvt8(const float* __restrict__ in,
                                            u16* __restrict__ out) {
  const size_t i = ((size_t)blockIdx.x * 256 + threadIdx.x) * 8;
  f32x4 a = *(const f32x4*)&in[i];
  f32x4 b = *(const f32x4*)&in[i + 4];
  bf16x8 h;
#pragma unroll
  for (int u = 0; u < 4; u++) h[u] = (short)f2bf(a[u]);
#pragma unroll
  for (int u = 0; u < 4; u++) h[4 + u] = (short)f2bf(b[u]);
  *(bf16x8*)&out[i] = h;
}

// ---------------------------------------------------------------------------
// bf16 transpose per batch: in [R,C] -> out [C,R], 64x64 LDS tiles
// ---------------------------------------------------------------------------
__global__ __launch_bounds__(256) void transpose_bf16(const u16* __restrict__ in,
                                                      u16* __restrict__ out,
                                                      int R, int C) {
  const int z = blockIdx.z;
  const u16* I = in + (size_t)z * R * C;
  u16* O = out + (size_t)z * R * C;
  __shared__ u16 t[64][72];
  const int r0 = blockIdx.y * 64, c0 = blockIdx.x * 64;
  const int tid = threadIdx.x;
#pragma unroll
  for (int i = 0; i < 2; i++) {
    int e = (i * 256 + tid) * 8;
    int r = e >> 6, c = e & 63;
    bf16x8 v = *(const bf16x8*)&I[(size_t)(r0 + r) * C + c0 + c];
#pragma unroll
    for (int u = 0; u < 8; u++) t[r][c + u] = (u16)v[u];
  }
  __syncthreads();
#pragma unroll
  for (int i = 0; i < 2; i++) {
    int e = (i * 256 + tid) * 8;
    int orow = e >> 6, oc = e & 63;
    bf16x8 v;
#pragma unroll
    for (int u = 0; u < 8; u++) v[u] = (short)t[oc + u][orow];
    *(bf16x8*)&O[(size_t)(c0 + orow) * R + r0 + oc] = v;
  }
}

// ---------------------------------------------------------------------------
// row softmax in-place on bf16 rows of length 2048 (256 thr -> 8/thr)
// ---------------------------------------------------------------------------
__global__ __launch_bounds__(256) void softmax_rows(u16* __restrict__ p) {
  const size_t base = (size_t)blockIdx.x * 2048;
  const int tid = threadIdx.x, lane = tid & 63, wv = tid >> 6;
  bf16x8 v = *(const bf16x8*)&p[base + tid * 8];
  float f[8];
#pragma unroll
  for (int u = 0; u < 8; u++) f[u] = bf2f((u16)v[u]);
  float mx = f[0];
#pragma unroll
  for (int u = 1; u < 8; u++) mx = fmaxf(mx, f[u]);
#pragma unroll
  for (int o = 32; o; o >>= 1) mx = fmaxf(mx, __shfl_xor(mx, o, 64));
  __shared__ float rm[4], rs[4];
  if (lane == 0) rm[wv] = mx;
  __syncthreads();
  mx = fmaxf(fmaxf(rm[0], rm[1]), fmaxf(rm[2], rm[3]));
  float s = 0.f, e[8];
#pragma unroll
  for (int u = 0; u < 8; u++) {
    e[u] = __expf(f[u] - mx);
    s += e[u];
  }
#pragma unroll
  for (int o = 32; o; o >>= 1) s += __shfl_xor(s, o, 64);
  if (lane == 0) rs[wv] = s;
  __syncthreads();
  s = rs[0] + rs[1] + rs[2] + rs[3];
  float inv = 1.f / s;
  bf16x8 o8;
#pragma unroll
  for (int u = 0; u < 8; u++) o8[u] = (short)f2bf(e[u] * inv);
  *(bf16x8*)&p[base + tid * 8] = o8;
}

// ---------------------------------------------------------------------------
// LayerNorm rows of 1024 fp32 -> d_out
// ---------------------------------------------------------------------------
__global__ __launch_bounds__(256) void ln_rows(const float* __restrict__ x,
                                               const float* __restrict__ gamma,
                                               const float* __restrict__ beta,
                                               float* __restrict__ out) {
  const size_t base = (size_t)blockIdx.x * 1024;
  const int tid = threadIdx.x, lane = tid & 63, wv = tid >> 6;
  f32x4 v = *(const f32x4*)&x[base + tid * 4];
  float s = v[0] + v[1] + v[2] + v[3];
  float q = v[0] * v[0] + v[1] * v[1] + v[2] * v[2] + v[3] * v[3];
#pragma unroll
  for (int o = 32; o; o >>= 1) {
    s += __shfl_xor(s, o, 64);
    q += __shfl_xor(q, o, 64);
  }
  __shared__ float rs[4], rq[4];
  if (lane == 0) {
    rs[wv] = s;
    rq[wv] = q;
  }
  __syncthreads();
  s = rs[0] + rs[1] + rs[2] + rs[3];
  q = rq[0] + rq[1] + rq[2] + rq[3];
  float mean = s * (1.f / 1024.f);
  float var = q * (1.f / 1024.f) - mean * mean;
  float rstd = rsqrtf(var + 1e-5f);
  f32x4 g = *(const f32x4*)&gamma[tid * 4];
  f32x4 b = *(const f32x4*)&beta[tid * 4];
  f32x4 o;
#pragma unroll
  for (int u = 0; u < 4; u++) o[u] = (v[u] - mean) * rstd * g[u] + b[u];
  *(f32x4*)&out[base + tid * 4] = o;
}

// ---------------------------------------------------------------------------
extern "C" void kernel_launch(void* const* d_in, const int* in_sizes, int n_in,
                              void* d_out, int out_size, void* d_ws,
                              size_t ws_size, hipStream_t stream) {
  (void)in_sizes; (void)n_in; (void)out_size; (void)ws_size;
  const float* q = (const float*)d_in[0];
  const float* k = (const float*)d_in[1];
  const float* v = (const float*)d_in[2];
  const float* Wq = (const float*)d_in[3];
  const float* Wk = (const float*)d_in[4];
  const float* bk = (const float*)d_in[5];
  const float* Wv = (const float*)d_in[6];
  const float* bv = (const float*)d_in[7];
  const float* Wo = (const float*)d_in[8];
  const float* bo = (const float*)d_in[9];
  const float* gamma = (const float*)d_in[10];
  const float* beta = (const float*)d_in[11];
  float* out = (float*)d_out;

  char* ws = (char*)d_ws;
  const size_t SZ_QKV = (size_t)16384 * 1024 * 2;  // 32 MiB
  u16* qh = (u16*)(ws);
  u16* kh = (u16*)(ws + SZ_QKV);
  u16* vh = (u16*)(ws + 2 * SZ_QKV);
  u16* vhT = (u16*)(ws + 3 * SZ_QKV);
  u16* probs = (u16*)(ws + 4 * SZ_QKV);     // 64 MiB, alive scores->PV
  u16* qkvb = probs;                        // 32 MiB A-cvt slot, dead by scores
  float* xbuf = (float*)(ws + 4 * SZ_QKV);  // overlays probs (dead by outproj)
  u16* attn = qh;                           // overlays qh (dead after scores)
  u16* Wqb = (u16*)(ws + 4 * SZ_QKV + (size_t)67108864);
  u16* Wkb = Wqb + 1048576;
  u16* Wvb = Wkb + 1048576;
  u16* Wob = Wvb + 1048576;

  // weights -> bf16
  cvt8<<<512, 256, 0, stream>>>(Wq, Wqb);
  cvt8<<<512, 256, 0, stream>>>(Wk, Wkb);
  cvt8<<<512, 256, 0, stream>>>(Wv, Wvb);
  cvt8<<<512, 256, 0, stream>>>(Wo, Wob);

  // projections: cvt input -> bf16 slot, then [16384,1024] x [1024,1024]^T
  dim3 gp(4, 64, 1);  // 256 blocks of 256x256
  cvt8<<<8192, 256, 0, stream>>>(q, qkvb);
  gemm_bt<false, false, false><<<gp, 512, 0, stream>>>(
      qkvb, Wqb, nullptr, nullptr, qh, 1024, 1024, 0, 0, 0, 0.125f);
  cvt8<<<8192, 256, 0, stream>>>(k, qkvb);
  gemm_bt<true, false, false><<<gp, 512, 0, stream>>>(
      qkvb, Wkb, bk, nullptr, kh, 1024, 1024, 0, 0, 0, 1.0f);
  cvt8<<<8192, 256, 0, stream>>>(v, qkvb);
  gemm_bt<true, false, false><<<gp, 512, 0, stream>>>(
      qkvb, Wvb, bv, nullptr, vh, 1024, 1024, 0, 0, 0, 1.0f);

  // vh [b,2048,1024] -> vhT [b,1024,2048]
  transpose_bf16<<<dim3(16, 32, 8), 256, 0, stream>>>(vh, vhT, 2048, 1024);

  // scores = qh @ kh^T per batch -> probs (bf16)
  gemm_bt<false, false, false><<<dim3(8, 8, 8), 512, 0, stream>>>(
      qh, kh, nullptr, nullptr, probs, 2048, 1024, 2097152LL, 2097152LL,
      4194304LL, 1.0f);

  // softmax rows in place
  softmax_rows<<<16384, 256, 0, stream>>>(probs);

  // attn = probs @ vhT^T per batch
  gemm_bt<false, false, false><<<dim3(4, 8, 8), 512, 0, stream>>>(
      probs, vhT, nullptr, nullptr, attn, 1024, 2048, 4194304LL, 2097152LL,
      2097152LL, 1.0f);

  // x = attn @ Wo^T + bo + q  (fp32)
  gemm_bt<true, true, true><<<dim3(4, 64, 1), 512, 0, stream>>>(
      attn, Wob, bo, q, xbuf, 1024, 1024, 0, 0, 0, 1.0f);

  // LayerNorm -> out
  ln_rows<<<16384, 256, 0, stream>>>(xbuf, gamma, beta, out);
}

// Round 8
// 414.659 us; speedup vs baseline: 1.5964x; 1.0344x over previous
//
#include <hip/hip_runtime.h>

typedef unsigned short u16;
typedef __attribute__((ext_vector_type(8))) short bf16x8;
typedef __attribute__((ext_vector_type(4))) short bf16x4;
typedef __attribute__((ext_vector_type(4))) float f32x4;

#define DEVINL static __device__ __forceinline__

// bf16 <-> f32 (RNE rounding)
DEVINL u16 f2bf(float x) {
  unsigned u = __float_as_uint(x);
  unsigned r = (u + 0x7FFFu + ((u >> 16) & 1u)) >> 16;
  return (u16)r;
}
DEVINL float bf2f(u16 h) { return __uint_as_float(((unsigned)h) << 16); }

// async global->LDS, 16B per lane (wave-uniform LDS base + lane*16 pattern)
DEVINL void gload_lds16(const u16* g, u16* l) {
  __builtin_amdgcn_global_load_lds(
      (const __attribute__((address_space(1))) void*)g,
      (__attribute__((address_space(3))) void*)l, 16, 0, 0);
}

// Row-pair granule swizzle for a [256 rows][32 cols] bf16 operand tile.
// LDS granule g (16B) = row-pair p=g>>3, slot w=g&7; logical location:
//   w' = w ^ (p&7);  row = 2p + (w'>>2);  kslot = w'&3.
// Verified zero bank conflicts on HW (r6: SQ_LDS_BANK_CONFLICT 6.3M -> 0).
DEVINL int swzg(int r, int s) {
  return ((r >> 1) << 3) + ((((r & 1) << 2) | s) ^ ((r >> 1) & 7));
}
// granule -> logical (row, kslot)
DEVINL void g2rk(int g, int& row, int& ks) {
  int p = g >> 3, w = (g & 7) ^ (p & 7);
  row = p * 2 + (w >> 2);
  ks = w & 3;
}

// Stage one bf16 operand tile [256][32] into LDS (2 gload instr per thread).
DEVINL void stage_half(const u16* gbase, int K, u16* ldst, int tid) {
#pragma unroll
  for (int i = 0; i < 2; i++) {
    int g = i * 512 + tid;
    int row, ks;
    g2rk(g, row, ks);
    gload_lds16(gbase + (size_t)row * K + ks * 8, ldst + g * 8);
  }
}

// ---------------------------------------------------------------------------
// GEMM: C[M,N] = scale*(A[M,K] * B[N,K]^T bf16) [+bias] [+resid]
// A_F32: A is fp32 in global; reg-staged (f32x4 loads -> RNE cvt ->
//        swizzled ds_write_b128) -- fuses the input conversion (saves a
//        separate 96MB cvt pass). B always via global_load_lds.
// TRANSV: epilogue writes C transposed per 2048-row batch (vhT layout),
//        folding the V transpose kernel away.
// Core (unchanged from r6, best measured): 256x256 tile, BK=32, 512 thr
// (8 waves 2Mx4N), 3-buffer LDS (96KB), 2-deep prefetch, counted vmcnt
// (never 0 in steady state), one barrier per K-tile, setprio on MFMA,
// bijective XCD block swizzle.
// ---------------------------------------------------------------------------
template <bool A_F32, bool HAS_BIAS, bool RESID, bool OUT_F32, bool TRANSV>
__global__ __launch_bounds__(512, 2) void gemm_bt(
    const void* __restrict__ Ap_, const u16* __restrict__ Bp,
    const float* __restrict__ bias, const float* __restrict__ resid,
    void* __restrict__ Cp, int N, int K, long long Az, long long Bz,
    long long Cz, float scale) {
  const int gx = gridDim.x, gy = gridDim.y;
  int lin = blockIdx.x + gx * (blockIdx.y + gy * blockIdx.z);
  const int nwg = gx * gy * gridDim.z;
  if ((nwg & 7) == 0) {
    const int chunk = nwg >> 3;
    lin = (lin & 7) * chunk + (lin >> 3);
  }
  const int bz = lin / (gx * gy);
  const int rem = lin - bz * gx * gy;
  const int m0 = (rem / gx) * 256, n0 = (rem % gx) * 256;

  const int tid = threadIdx.x, lane = tid & 63, wv = tid >> 6;
  const int wr = wv >> 2, wc = wv & 3, lr = lane & 15, lh = lane >> 4;

  // 3 bufs x (A 16KB + B 16KB) = 96 KB
  __shared__ u16 lds[3 * 16384];

  const u16* A16 = nullptr;
  const float* A32 = nullptr;
  if constexpr (A_F32)
    A32 = (const float*)Ap_ + (size_t)bz * Az + (size_t)m0 * K;
  else
    A16 = (const u16*)Ap_ + (size_t)bz * Az + (size_t)m0 * K;
  const u16* B = Bp + (size_t)bz * Bz + (size_t)n0 * K;

  f32x4 acc[8][4] = {};
  const int nt = K >> 5;

  // ---- prologue: tiles 0,1 resident/staged ----
  if constexpr (A_F32) {
#pragma unroll
    for (int t = 0; t < 2; t++) {
      u16* dstA = &lds[t * 16384];
#pragma unroll
      for (int i = 0; i < 2; i++) {
        int g = i * 512 + tid, row, ks;
        g2rk(g, row, ks);
        const float* src = A32 + (size_t)row * K + t * 32 + ks * 8;
        f32x4 a = *(const f32x4*)src;
        f32x4 b = *(const f32x4*)(src + 4);
        bf16x8 h;
#pragma unroll
        for (int u = 0; u < 4; u++) {
          h[u] = (short)f2bf(a[u]);
          h[4 + u] = (short)f2bf(b[u]);
        }
        *(bf16x8*)&dstA[g * 8] = h;
      }
      stage_half(B + t * 32, K, &lds[t * 16384 + 8192], tid);
    }
    asm volatile("s_waitcnt vmcnt(2) lgkmcnt(0)" ::: "memory");
  } else {
    stage_half(A16, K, &lds[0], tid);
    stage_half(B, K, &lds[8192], tid);
    stage_half(A16 + 32, K, &lds[16384], tid);
    stage_half(B + 32, K, &lds[16384 + 8192], tid);
    asm volatile("s_waitcnt vmcnt(4)" ::: "memory");
  }
  __builtin_amdgcn_s_barrier();

  int d = 0;
  for (int t = 0; t < nt; ++t) {
    const u16* la = &lds[d * 16384];
    const u16* lb = la + 8192;
    int dn = d + 2;
    if (dn >= 3) dn -= 3;
    const bool doPre = (t + 2) < nt;

    // ---- phase 0: B frags + A frags m0..3; issue next-A loads / stage A ----
    bf16x8 bfv[4], af[4];
#pragma unroll
    for (int n = 0; n < 4; n++) {
      int row = wc * 64 + n * 16 + lr;
      bfv[n] = *(const bf16x8*)&lb[swzg(row, lh) * 8];
    }
#pragma unroll
    for (int m = 0; m < 4; m++) {
      int row = wr * 128 + m * 16 + lr;
      af[m] = *(const bf16x8*)&la[swzg(row, lh) * 8];
    }
    f32x4 pre0, pre1;
    if constexpr (A_F32) {
      if (doPre) {  // granule 0 of A(t+2): issue early, consume in phase 1
        int row, ks;
        g2rk(tid, row, ks);
        const float* src = A32 + (size_t)row * K + (t + 2) * 32 + ks * 8;
        pre0 = *(const f32x4*)src;
        pre1 = *(const f32x4*)(src + 4);
      }
    } else {
      if (doPre) stage_half(A16 + (size_t)(t + 2) * 32, K, &lds[dn * 16384], tid);
    }
    __builtin_amdgcn_s_setprio(1);
#pragma unroll
    for (int m = 0; m < 4; m++)
#pragma unroll
      for (int n = 0; n < 4; n++)
        acc[m][n] = __builtin_amdgcn_mfma_f32_16x16x32_bf16(af[m], bfv[n],
                                                            acc[m][n], 0, 0, 0);
    __builtin_amdgcn_s_setprio(0);

    // ---- phase 1: A frags m4..7; stage B(t+2); A_F32: cvt+ds_write ----
#pragma unroll
    for (int m = 0; m < 4; m++) {
      int row = wr * 128 + (m + 4) * 16 + lr;
      af[m] = *(const bf16x8*)&la[swzg(row, lh) * 8];
    }
    if (doPre) stage_half(B + (size_t)(t + 2) * 32, K, &lds[dn * 16384 + 8192], tid);
    if constexpr (A_F32) {
      if (doPre) {
        u16* dstA = &lds[dn * 16384];
        bf16x8 h0;
#pragma unroll
        for (int u = 0; u < 4; u++) {
          h0[u] = (short)f2bf(pre0[u]);
          h0[4 + u] = (short)f2bf(pre1[u]);
        }
        *(bf16x8*)&dstA[tid * 8] = h0;
        int g = 512 + tid, row, ks;
        g2rk(g, row, ks);
        const float* src = A32 + (size_t)row * K + (t + 2) * 32 + ks * 8;
        f32x4 a = *(const f32x4*)src;
        f32x4 b = *(const f32x4*)(src + 4);
        bf16x8 h1;
#pragma unroll
        for (int u = 0; u < 4; u++) {
          h1[u] = (short)f2bf(a[u]);
          h1[4 + u] = (short)f2bf(b[u]);
        }
        *(bf16x8*)&dstA[g * 8] = h1;
      }
    }
    __builtin_amdgcn_s_setprio(1);
#pragma unroll
    for (int m = 0; m < 4; m++)
#pragma unroll
      for (int n = 0; n < 4; n++)
        acc[m + 4][n] = __builtin_amdgcn_mfma_f32_16x16x32_bf16(
            af[m], bfv[n], acc[m + 4][n], 0, 0, 0);
    __builtin_amdgcn_s_setprio(0);

    // ---- tile boundary: counted vmcnt (loads for t+2 stay in flight) ----
    if constexpr (A_F32) {
      if (doPre)
        asm volatile("s_waitcnt vmcnt(2) lgkmcnt(0)" ::: "memory");
      else if (t + 1 < nt)
        asm volatile("s_waitcnt vmcnt(0) lgkmcnt(0)" ::: "memory");
    } else {
      if (doPre)
        asm volatile("s_waitcnt vmcnt(4)" ::: "memory");
      else if (t + 1 < nt)
        asm volatile("s_waitcnt vmcnt(0)" ::: "memory");
    }
    if (t + 1 < nt) __builtin_amdgcn_s_barrier();
    if (++d == 3) d = 0;
  }

  // ---- epilogue: C/D layout col=lane&15, row=(lane>>4)*4+reg ----
  if constexpr (TRANSV) {
    // write C^T per 2048-row batch: vhT[b][col][s], s = row % 2048.
    u16* Ch = (u16*)Cp;
#pragma unroll
    for (int m = 0; m < 8; m++) {
      int row0 = m0 + wr * 128 + m * 16 + lh * 4;
      int b = row0 >> 11, s = row0 & 2047;
#pragma unroll
      for (int n = 0; n < 4; n++) {
        int col = n0 + wc * 64 + n * 16 + lr;
        bf16x4 pack;
#pragma unroll
        for (int j = 0; j < 4; j++) {
          float val = acc[m][n][j] * scale;
          if constexpr (HAS_BIAS) val += bias[col];
          pack[j] = (short)f2bf(val);
        }
        *(bf16x4*)&Ch[((size_t)b << 21) + ((size_t)col << 11) + s] = pack;
      }
    }
  } else {
    float* Cf = nullptr;
    u16* Ch = nullptr;
    if constexpr (OUT_F32)
      Cf = (float*)Cp + (size_t)bz * Cz;
    else
      Ch = (u16*)Cp + (size_t)bz * Cz;
#pragma unroll
    for (int m = 0; m < 8; m++) {
#pragma unroll
      for (int j = 0; j < 4; j++) {
        int row = m0 + wr * 128 + m * 16 + lh * 4 + j;
#pragma unroll
        for (int n = 0; n < 4; n++) {
          int col = n0 + wc * 64 + n * 16 + lr;
          float val = acc[m][n][j] * scale;
          if constexpr (HAS_BIAS) val += bias[col];
          if constexpr (RESID) val += resid[(size_t)row * N + col];
          if constexpr (OUT_F32)
            Cf[(size_t)row * N + col] = val;
          else
            Ch[(size_t)row * N + col] = f2bf(val);
        }
      }
    }
  }
}

// ---------------------------------------------------------------------------
// fused weight cvt: 4 x [1024x1024] fp32 -> contiguous bf16 (one launch)
// ---------------------------------------------------------------------------
__global__ __launch_bounds__(256) void cvt8w(const float* __restrict__ w0,
                                             const float* __restrict__ w1,
                                             const float* __restrict__ w2,
                                             const float* __restrict__ w3,
                                             u16* __restrict__ out) {
  const int wsel = blockIdx.x >> 9;
  const float* in = wsel == 0 ? w0 : wsel == 1 ? w1 : wsel == 2 ? w2 : w3;
  const size_t i = ((size_t)(blockIdx.x & 511) * 256 + threadIdx.x) * 8;
  f32x4 a = *(const f32x4*)&in[i];
  f32x4 b = *(const f32x4*)&in[i + 4];
  bf16x8 h;
#pragma unroll
  for (int u = 0; u < 4; u++) {
    h[u] = (short)f2bf(a[u]);
    h[4 + u] = (short)f2bf(b[u]);
  }
  *(bf16x8*)&out[(size_t)wsel * 1048576 + i] = h;
}

// ---------------------------------------------------------------------------
// row softmax in-place on bf16 rows of length 2048 (256 thr -> 8/thr)
// ---------------------------------------------------------------------------
__global__ __launch_bounds__(256) void softmax_rows(u16* __restrict__ p) {
  const size_t base = (size_t)blockIdx.x * 2048;
  const int tid = threadIdx.x, lane = tid & 63, wv = tid >> 6;
  bf16x8 v = *(const bf16x8*)&p[base + tid * 8];
  float f[8];
#pragma unroll
  for (int u = 0; u < 8; u++) f[u] = bf2f((u16)v[u]);
  float mx = f[0];
#pragma unroll
  for (int u = 1; u < 8; u++) mx = fmaxf(mx, f[u]);
#pragma unroll
  for (int o = 32; o; o >>= 1) mx = fmaxf(mx, __shfl_xor(mx, o, 64));
  __shared__ float rm[4], rs[4];
  if (lane == 0) rm[wv] = mx;
  __syncthreads();
  mx = fmaxf(fmaxf(rm[0], rm[1]), fmaxf(rm[2], rm[3]));
  float s = 0.f, e[8];
#pragma unroll
  for (int u = 0; u < 8; u++) {
    e[u] = __expf(f[u] - mx);
    s += e[u];
  }
#pragma unroll
  for (int o = 32; o; o >>= 1) s += __shfl_xor(s, o, 64);
  if (lane == 0) rs[wv] = s;
  __syncthreads();
  s = rs[0] + rs[1] + rs[2] + rs[3];
  float inv = 1.f / s;
  bf16x8 o8;
#pragma unroll
  for (int u = 0; u < 8; u++) o8[u] = (short)f2bf(e[u] * inv);
  *(bf16x8*)&p[base + tid * 8] = o8;
}

// ---------------------------------------------------------------------------
// LayerNorm rows of 1024 fp32 -> d_out
// ---------------------------------------------------------------------------
__global__ __launch_bounds__(256) void ln_rows(const float* __restrict__ x,
                                               const float* __restrict__ gamma,
                                               const float* __restrict__ beta,
                                               float* __restrict__ out) {
  const size_t base = (size_t)blockIdx.x * 1024;
  const int tid = threadIdx.x, lane = tid & 63, wv = tid >> 6;
  f32x4 v = *(const f32x4*)&x[base + tid * 4];
  float s = v[0] + v[1] + v[2] + v[3];
  float q = v[0] * v[0] + v[1] * v[1] + v[2] * v[2] + v[3] * v[3];
#pragma unroll
  for (int o = 32; o; o >>= 1) {
    s += __shfl_xor(s, o, 64);
    q += __shfl_xor(q, o, 64);
  }
  __shared__ float rs[4], rq[4];
  if (lane == 0) {
    rs[wv] = s;
    rq[wv] = q;
  }
  __syncthreads();
  s = rs[0] + rs[1] + rs[2] + rs[3];
  q = rq[0] + rq[1] + rq[2] + rq[3];
  float mean = s * (1.f / 1024.f);
  float var = q * (1.f / 1024.f) - mean * mean;
  float rstd = rsqrtf(var + 1e-5f);
  f32x4 g = *(const f32x4*)&gamma[tid * 4];
  f32x4 b = *(const f32x4*)&beta[tid * 4];
  f32x4 o;
#pragma unroll
  for (int u = 0; u < 4; u++) o[u] = (v[u] - mean) * rstd * g[u] + b[u];
  *(f32x4*)&out[base + tid * 4] = o;
}

// ---------------------------------------------------------------------------
extern "C" void kernel_launch(void* const* d_in, const int* in_sizes, int n_in,
                              void* d_out, int out_size, void* d_ws,
                              size_t ws_size, hipStream_t stream) {
  (void)in_sizes; (void)n_in; (void)out_size; (void)ws_size;
  const float* q = (const float*)d_in[0];
  const float* k = (const float*)d_in[1];
  const float* v = (const float*)d_in[2];
  const float* Wq = (const float*)d_in[3];
  const float* Wk = (const float*)d_in[4];
  const float* bk = (const float*)d_in[5];
  const float* Wv = (const float*)d_in[6];
  const float* bv = (const float*)d_in[7];
  const float* Wo = (const float*)d_in[8];
  const float* bo = (const float*)d_in[9];
  const float* gamma = (const float*)d_in[10];
  const float* beta = (const float*)d_in[11];
  float* out = (float*)d_out;

  char* ws = (char*)d_ws;
  const size_t SZ_QKV = (size_t)16384 * 1024 * 2;  // 32 MiB
  u16* qh = (u16*)(ws);
  u16* kh = (u16*)(ws + SZ_QKV);
  u16* vhT = (u16*)(ws + 3 * SZ_QKV);       // [b][1024][2048], written by V-proj
  u16* probs = (u16*)(ws + 4 * SZ_QKV);     // 64 MiB, alive scores->PV
  float* xbuf = (float*)(ws + 4 * SZ_QKV);  // overlays probs (dead by outproj)
  u16* attn = qh;                           // overlays qh (dead after scores)
  u16* Wqb = (u16*)(ws + 4 * SZ_QKV + (size_t)67108864);
  u16* Wkb = Wqb + 1048576;
  u16* Wvb = Wkb + 1048576;
  u16* Wob = Wvb + 1048576;

  // all 4 weights -> bf16, one launch (dsts contiguous from Wqb)
  cvt8w<<<2048, 256, 0, stream>>>(Wq, Wk, Wv, Wo, Wqb);

  // projections: fp32 A fused-cvt inside GEMM; [16384,1024] x [1024,1024]^T
  dim3 gp(4, 64, 1);  // 256 blocks of 256x256
  gemm_bt<true, false, false, false, false><<<gp, 512, 0, stream>>>(
      q, Wqb, nullptr, nullptr, qh, 1024, 1024, 0, 0, 0, 0.125f);
  gemm_bt<true, true, false, false, false><<<gp, 512, 0, stream>>>(
      k, Wkb, bk, nullptr, kh, 1024, 1024, 0, 0, 0, 1.0f);
  // V-proj writes vhT directly (transposed epilogue) — transpose kernel gone
  gemm_bt<true, true, false, false, true><<<gp, 512, 0, stream>>>(
      v, Wvb, bv, nullptr, vhT, 1024, 1024, 0, 0, 0, 1.0f);

  // scores = qh @ kh^T per batch -> probs (bf16)
  gemm_bt<false, false, false, false, false><<<dim3(8, 8, 8), 512, 0, stream>>>(
      qh, kh, nullptr, nullptr, probs, 2048, 1024, 2097152LL, 2097152LL,
      4194304LL, 1.0f);

  // softmax rows in place
  softmax_rows<<<16384, 256, 0, stream>>>(probs);

  // attn = probs @ vhT^T per batch
  gemm_bt<false, false, false, false, false><<<dim3(4, 8, 8), 512, 0, stream>>>(
      probs, vhT, nullptr, nullptr, attn, 1024, 2048, 4194304LL, 2097152LL,
      2097152LL, 1.0f);

  // x = attn @ Wo^T + bo + q  (fp32)
  gemm_bt<false, true, true, true, false><<<dim3(4, 64, 1), 512, 0, stream>>>(
      attn, Wob, bo, q, xbuf, 1024, 1024, 0, 0, 0, 1.0f);

  // LayerNorm -> out
  ln_rows<<<16384, 256, 0, stream>>>(xbuf, gamma, beta, out);
}